// Round 13
// baseline (215.920 us; speedup 1.0000x reference)
//
#include <hip/hip_runtime.h>
#include <hip/hip_bf16.h>
#include <cstdint>

// Problem: B=4, T=1024, C=1024, H=16, D=64, MAX_LEN=1024, NPOS=2047
// Pipeline (R29, resubmitted unchanged in R31 -- container failure, never ran):
//   cvt3: x, qkv_w, proj_w fp32 -> bf16 in ws (measured ~96% HBM peak: done)
//   table_reduce rel_pos_emb -> (2047,16)  [1-wave-per-head]
//   gemm_bt<0>: qkv = xb @ qwb^T + b -> scatter bf16; Q,K (B,H,T,D), V (B,H,D,T)
//   attn_mfma: 32x32 lane-local softmax, KVBLK=64 + defer-max, 4-way KV-SPLIT
//   gemm_bt<1>: out = y @ pwb^T + b -> fp32 d_out
//
// R27 measured: 193.2 total (baseline restored). gemm0 stable 44.0-44.5us
// (VGPR-32 codegen is the stable lottery outcome). attn ~40-43us, occ 12% =
// structural grid cap (2048 waves / 1024 SIMD = 2/SIMD) x 32:1 causal skew.
// In-wave latency fixes all failed (R19); issue-work fixes worked (R21/R23).
// Residual latency needs TLP -> kv-split is the only new parallelism source.
// R29 change (attn only): 4-way kv-split. Block 256thr/4 waves = one slice;
// wave w takes contiguous tile chunk [w*ceil(nt/4),...); own online softmax;
// waves 0-2 post (mi,li,oacc) to LDS (26KB), 1 barrier, wave 3 merges
// (m*=max, w_i=exp(m_i-m*), O=sum w_i O_i, l=sum w_i l_i; partner symmetry
// preserved -> final shfl_xor(32) li-sum unchanged) and writes y. Waves
// 2048 -> 8192, max wave length 32 -> 8 tiles.
//
// Workspace layout (bytes):
//   xb   @ 0         : 4096x1024 bf16  (8 MB)
//   qwb  @ 8388608   : 3072x1024 bf16  (6 MB)
//   pwb  @ 14680064  : 1024x1024 bf16  (2 MB)
//   table@ 16777216  : 2047x16 f32     (128 KB)
//   qkvb @ 16908288  : (3,4,16,64K) bf16 (24 MB)
//   y    @ 42074112  : 4096x1024 bf16  (8 MB)

typedef __bf16 bf16x8 __attribute__((ext_vector_type(8)));
typedef float f32x4 __attribute__((ext_vector_type(4)));
typedef float f32x16 __attribute__((ext_vector_type(16)));

__device__ __forceinline__ float bf2f(unsigned short u) {
    return __uint_as_float(((unsigned)u) << 16);
}
__device__ __forceinline__ unsigned short f2bf(float f) {
    __hip_bfloat16 h = __float2bfloat16(f);
    return *reinterpret_cast<unsigned short*>(&h);
}
__device__ __forceinline__ unsigned pk2(float a, float b) {
    return (unsigned)f2bf(a) | ((unsigned)f2bf(b) << 16);
}
__device__ __forceinline__ int4 cvt8(float4 a, float4 b) {
    union { unsigned short s[8]; int4 v; } u;
    u.s[0] = f2bf(a.x); u.s[1] = f2bf(a.y); u.s[2] = f2bf(a.z); u.s[3] = f2bf(a.w);
    u.s[4] = f2bf(b.x); u.s[5] = f2bf(b.y); u.s[6] = f2bf(b.z); u.s[7] = f2bf(b.w);
    return u.v;
}

// async global->LDS, 16B per lane. LDS dest must be linear base+lane*16.
__device__ __forceinline__ void gload16(const void* g, void* l) {
    __builtin_amdgcn_global_load_lds(
        reinterpret_cast<const __attribute__((address_space(1))) unsigned int*>(
            reinterpret_cast<uintptr_t>(g)),
        reinterpret_cast<__attribute__((address_space(3))) unsigned int*>(
            reinterpret_cast<uintptr_t>(l)),
        16, 0, 0);
}

// ---------------- fp32 -> bf16 one-shot convert (x, qkv_w, proj_w) ----------
__global__ __launch_bounds__(256) void cvt3(const float* __restrict__ x,
                                            const float* __restrict__ w1,
                                            const float* __restrict__ w2,
                                            unsigned short* __restrict__ ox,
                                            unsigned short* __restrict__ ow1,
                                            unsigned short* __restrict__ ow2) {
    const int i = blockIdx.x * 256 + threadIdx.x;
    const float* s; unsigned short* d; int li;
    if (i < 524288)      { s = x;  d = ox;  li = i; }
    else if (i < 917504) { s = w1; d = ow1; li = i - 524288; }
    else                 { s = w2; d = ow2; li = i - 917504; }
    const float4 a = *(const float4*)(s + (size_t)li * 8);
    const float4 b = *(const float4*)(s + (size_t)li * 8 + 4);
    *(int4*)(d + (size_t)li * 8) = cvt8(a, b);
}

// ---------------- rel_pos_emb (2047,1024) -> table (2047,16) ----------------
// 1024 thr = 16 waves; wave w sums head w's 64 d's: coalesced load + single
// 6-shfl tree.
__global__ __launch_bounds__(1024) void table_reduce(const float* __restrict__ rel,
                                                     float* __restrict__ table) {
    const int p = blockIdx.x;
    const int w = threadIdx.x >> 6, lane = threadIdx.x & 63;
    float v = rel[(size_t)p * 1024 + w * 64 + lane];
#pragma unroll
    for (int o = 32; o; o >>= 1) v += __shfl_xor(v, o, 64);
    if (lane == 0) table[p * 16 + w] = v;
}

// ---------------- bf16 MFMA GEMM: C = A B^T + bias (R12-exact) --------------
// 512 threads, 8 waves: wr=wave&1 (64-row half), wc=wave>>1 (32-col quarter).
// Staging: global_load_lds width=16; thread t covers row t>>2, shorts (t&3)*8
// -> LDS linear [128][32]. One call per matrix per K-step (8 KB each).
// EPI=0: scatter bf16 into qkv planes (Q,K [t][d], V [d][t]). EPI=1: fp32 out.
template <int EPI>
__global__ __launch_bounds__(512) void gemm_bt(const unsigned short* __restrict__ A,
                                               const unsigned short* __restrict__ B,
                                               const float* __restrict__ bias,
                                               unsigned short* __restrict__ outb,
                                               float* __restrict__ outf,
                                               int M, int N, int K) {
    __shared__ __attribute__((aligned(16))) unsigned short As[128 * 32];
    __shared__ __attribute__((aligned(16))) unsigned short Bs[128 * 32];
    const int bm = blockIdx.x * 128, bn = blockIdx.y * 128;
    const int tid = threadIdx.x, lane = tid & 63, wave = tid >> 6;
    const int wr = wave & 1, wc = wave >> 1;  // wc in 0..3
    const int quad = lane >> 4, lm = lane & 15;

    const int srow = tid >> 2;        // 0..127
    const int scol = (tid & 3) * 8;   // shorts
    const unsigned short* Ap = A + (size_t)(bm + srow) * K + scol;
    const unsigned short* Bp = B + (size_t)(bn + srow) * K + scol;
    unsigned short* AsW = &As[tid * 8];   // == row srow, col scol (linear)
    unsigned short* BsW = &Bs[tid * 8];

    f32x4 acc[4][2];
#pragma unroll
    for (int r = 0; r < 4; ++r)
#pragma unroll
        for (int c = 0; c < 2; ++c) acc[r][c] = (f32x4){0.f, 0.f, 0.f, 0.f};

    for (int kk = 0; kk < K; kk += 32) {
        gload16(Ap + kk, AsW);
        gload16(Bp + kk, BsW);
        __syncthreads();  // compiler emits vmcnt(0) drain before s_barrier

        bf16x8 af[4], bfr[2];
#pragma unroll
        for (int r = 0; r < 4; ++r)
            af[r] = *(const bf16x8*)(&As[(64 * wr + 16 * r + lm) * 32 + quad * 8]);
#pragma unroll
        for (int c = 0; c < 2; ++c)
            bfr[c] = *(const bf16x8*)(&Bs[(32 * wc + 16 * c + lm) * 32 + quad * 8]);
#pragma unroll
        for (int r = 0; r < 4; ++r)
#pragma unroll
            for (int c = 0; c < 2; ++c)
                acc[r][c] = __builtin_amdgcn_mfma_f32_16x16x32_bf16(af[r], bfr[c], acc[r][c], 0, 0, 0);
        __syncthreads();
    }

    // C/D layout: col = lane&15, row = (lane>>4)*4 + reg
#pragma unroll
    for (int r = 0; r < 4; ++r)
#pragma unroll
        for (int c = 0; c < 2; ++c)
#pragma unroll
            for (int i = 0; i < 4; ++i) {
                const int row = bm + 64 * wr + 16 * r + quad * 4 + i;
                const int col = bn + 32 * wc + 16 * c + lm;
                const float v = acc[r][c][i] + bias[col];
                if (EPI == 0) {
                    const int b = row >> 10, t = row & 1023;
                    const int s3 = col >> 10, rem = col & 1023;
                    const int h = rem >> 6, d = rem & 63;
                    const size_t base = (((size_t)s3 * 4 + b) * 16 + h) * 65536;
                    const size_t off = base + (s3 == 2 ? (size_t)d * 1024 + t
                                                       : (size_t)t * 64 + d);
                    outb[off] = f2bf(v);
                } else {
                    outf[(size_t)row * N + col] = v;
                }
            }
}

// ---------------- MFMA flash causal attention (4-way kv-split) -------------
// 32x32 lane-local softmax, KVBLK=64 joint tiles + T13 defer-max.
#define LOADK(DST, KT)                                                        \
    do {                                                                      \
        const unsigned short* kr_ = Kg + (size_t)((KT) * 32 + l5) * 64 + hi8; \
        DST[0] = *(const bf16x8*)(kr_);                                       \
        DST[1] = *(const bf16x8*)(kr_ + 16);                                  \
        DST[2] = *(const bf16x8*)(kr_ + 32);                                  \
        DST[3] = *(const bf16x8*)(kr_ + 48);                                  \
    } while (0)

// Single 32-j tile (tail only; always-rescale path). Uses kA-style frag KF.
#define ATTN_TILE(KF, KT)                                                     \
    do {                                                                      \
        const int jb = (KT) * 32;                                             \
        const unsigned short* vb_ = Vtg + (size_t)l5 * 1024 + jb + hi8;       \
        const bf16x8 vf00 = *(const bf16x8*)(vb_);                            \
        const bf16x8 vf01 = *(const bf16x8*)(vb_ + 16);                       \
        const bf16x8 vf10 = *(const bf16x8*)(vb_ + 32768);                    \
        const bf16x8 vf11 = *(const bf16x8*)(vb_ + 32768 + 16);               \
        f32x16 s = {0.f};                                                     \
        _Pragma("unroll")                                                     \
        for (int t = 0; t < 4; ++t)                                           \
            s = __builtin_amdgcn_mfma_f32_32x32x16_bf16(KF[t], qf[t], s, 0, 0, 0); \
        float p[16];                                                          \
        _Pragma("unroll")                                                     \
        for (int reg = 0; reg < 16; ++reg) {                                  \
            const int j = jb + (reg & 3) + 8 * (reg >> 2) + 4 * hi;           \
            p[reg] = fmaf(s[reg], 0.125f, tb[q - j + 127]);                   \
        }                                                                     \
        if (jb + 31 > qbase) {                                                \
            _Pragma("unroll")                                                 \
            for (int reg = 0; reg < 16; ++reg) {                              \
                const int j = jb + (reg & 3) + 8 * (reg >> 2) + 4 * hi;       \
                p[reg] = (j <= q) ? p[reg] : -1e30f;                          \
            }                                                                 \
        }                                                                     \
        float mx = p[0];                                                      \
        _Pragma("unroll")                                                     \
        for (int reg = 1; reg < 16; ++reg) mx = fmaxf(mx, p[reg]);            \
        mx = fmaxf(mx, __shfl_xor(mx, 32, 64));                               \
        if (!__all(mx <= mi + 8.f)) {                                         \
            const float mnew = fmaxf(mi, mx);                                 \
            const float alpha = __expf(mi - mnew);                            \
            mi = mnew;                                                        \
            li *= alpha;                                                      \
            _Pragma("unroll")                                                 \
            for (int reg = 0; reg < 16; ++reg) {                              \
                oa0[reg] *= alpha;                                            \
                oa1[reg] *= alpha;                                            \
            }                                                                 \
        }                                                                     \
        float lsum = 0.f;                                                     \
        _Pragma("unroll")                                                     \
        for (int reg = 0; reg < 16; ++reg) {                                  \
            p[reg] = __expf(p[reg] - mi);                                     \
            lsum += p[reg];                                                   \
        }                                                                     \
        li += lsum;                                                           \
        const unsigned P0 = pk2(p[0], p[1]),   P1 = pk2(p[2], p[3]);          \
        const unsigned P2 = pk2(p[4], p[5]),   P3 = pk2(p[6], p[7]);          \
        const unsigned P4 = pk2(p[8], p[9]),   P5 = pk2(p[10], p[11]);        \
        const unsigned P6 = pk2(p[12], p[13]), P7 = pk2(p[14], p[15]);        \
        const unsigned R0 = __shfl_xor(hi ? P0 : P2, 32, 64);                 \
        const unsigned R1 = __shfl_xor(hi ? P1 : P3, 32, 64);                 \
        const unsigned R2 = __shfl_xor(hi ? P4 : P6, 32, 64);                 \
        const unsigned R3 = __shfl_xor(hi ? P5 : P7, 32, 64);                 \
        union { unsigned w[4]; bf16x8 v; } bq0, bq1;                          \
        bq0.w[0] = hi ? R0 : P0;  bq0.w[1] = hi ? R1 : P1;                    \
        bq0.w[2] = hi ? P2 : R0;  bq0.w[3] = hi ? P3 : R1;                    \
        bq1.w[0] = hi ? R2 : P4;  bq1.w[1] = hi ? R3 : P5;                    \
        bq1.w[2] = hi ? P6 : R2;  bq1.w[3] = hi ? P7 : R3;                    \
        oa0 = __builtin_amdgcn_mfma_f32_32x32x16_bf16(vf00, bq0.v, oa0, 0, 0, 0); \
        oa0 = __builtin_amdgcn_mfma_f32_32x32x16_bf16(vf01, bq1.v, oa0, 0, 0, 0); \
        oa1 = __builtin_amdgcn_mfma_f32_32x32x16_bf16(vf10, bq0.v, oa1, 0, 0, 0); \
        oa1 = __builtin_amdgcn_mfma_f32_32x32x16_bf16(vf11, bq1.v, oa1, 0, 0, 0); \
    } while (0)

// Pack+partner-exchange p[16] -> two PV B-frags (BQA, BQB).
#define PACKP(p, BQA, BQB)                                                    \
    do {                                                                      \
        const unsigned P0 = pk2(p[0], p[1]),   P1 = pk2(p[2], p[3]);          \
        const unsigned P2 = pk2(p[4], p[5]),   P3 = pk2(p[6], p[7]);          \
        const unsigned P4 = pk2(p[8], p[9]),   P5 = pk2(p[10], p[11]);        \
        const unsigned P6 = pk2(p[12], p[13]), P7 = pk2(p[14], p[15]);        \
        const unsigned R0 = __shfl_xor(hi ? P0 : P2, 32, 64);                 \
        const unsigned R1 = __shfl_xor(hi ? P1 : P3, 32, 64);                 \
        const unsigned R2 = __shfl_xor(hi ? P4 : P6, 32, 64);                 \
        const unsigned R3 = __shfl_xor(hi ? P5 : P7, 32, 64);                 \
        BQA.w[0] = hi ? R0 : P0;  BQA.w[1] = hi ? R1 : P1;                    \
        BQA.w[2] = hi ? P2 : R0;  BQA.w[3] = hi ? P3 : R1;                    \
        BQB.w[0] = hi ? R2 : P4;  BQB.w[1] = hi ? R3 : P5;                    \
        BQB.w[2] = hi ? P6 : R2;  BQB.w[3] = hi ? P7 : R3;                    \
    } while (0)

// Joint KVBLK=64: subtiles KT (kA) and KT+1 (kB); ONE softmax update.
// Prefetch bounded by kend (wave's chunk end).
#define ATTN_TILE2(KT)                                                        \
    do {                                                                      \
        const int jb = (KT) * 32;                                             \
        const unsigned short* vb_ = Vtg + (size_t)l5 * 1024 + jb + hi8;       \
        const bf16x8 vf00 = *(const bf16x8*)(vb_);                            \
        const bf16x8 vf01 = *(const bf16x8*)(vb_ + 16);                       \
        const bf16x8 vf02 = *(const bf16x8*)(vb_ + 32);                       \
        const bf16x8 vf03 = *(const bf16x8*)(vb_ + 48);                       \
        const bf16x8 vf10 = *(const bf16x8*)(vb_ + 32768);                    \
        const bf16x8 vf11 = *(const bf16x8*)(vb_ + 32768 + 16);               \
        const bf16x8 vf12 = *(const bf16x8*)(vb_ + 32768 + 32);               \
        const bf16x8 vf13 = *(const bf16x8*)(vb_ + 32768 + 48);               \
        f32x16 s0v = {0.f}, s1v = {0.f};                                      \
        _Pragma("unroll")                                                     \
        for (int t = 0; t < 4; ++t) {                                         \
            s0v = __builtin_amdgcn_mfma_f32_32x32x16_bf16(kA[t], qf[t], s0v, 0, 0, 0); \
            s1v = __builtin_amdgcn_mfma_f32_32x32x16_bf16(kB[t], qf[t], s1v, 0, 0, 0); \
        }                                                                     \
        if ((KT) + 2 < kend) LOADK(kA, (KT) + 2);                             \
        if ((KT) + 3 < kend) LOADK(kB, (KT) + 3);                             \
        float p0[16], p1[16];                                                 \
        _Pragma("unroll")                                                     \
        for (int reg = 0; reg < 16; ++reg) {                                  \
            const int jo = (reg & 3) + 8 * (reg >> 2) + 4 * hi;               \
            p0[reg] = fmaf(s0v[reg], 0.125f, tb[q - jb - jo + 127]);          \
            p1[reg] = fmaf(s1v[reg], 0.125f, tb[q - jb - 32 - jo + 127]);     \
        }                                                                     \
        if (jb + 63 > qbase) {                                                \
            _Pragma("unroll")                                                 \
            for (int reg = 0; reg < 16; ++reg) {                              \
                const int jo = (reg & 3) + 8 * (reg >> 2) + 4 * hi;           \
                p0[reg] = (jb + jo <= q) ? p0[reg] : -1e30f;                  \
                p1[reg] = (jb + 32 + jo <= q) ? p1[reg] : -1e30f;             \
            }                                                                 \
        }                                                                     \
        float mx = p0[0];                                                     \
        _Pragma("unroll")                                                     \
        for (int reg = 1; reg < 16; ++reg) mx = fmaxf(mx, p0[reg]);           \
        _Pragma("unroll")                                                     \
        for (int reg = 0; reg < 16; ++reg) mx = fmaxf(mx, p1[reg]);           \
        mx = fmaxf(mx, __shfl_xor(mx, 32, 64));                               \
        if (!__all(mx <= mi + 8.f)) {                                         \
            const float mnew = fmaxf(mi, mx);                                 \
            const float alpha = __expf(mi - mnew);                            \
            mi = mnew;                                                        \
            li *= alpha;                                                      \
            _Pragma("unroll")                                                 \
            for (int reg = 0; reg < 16; ++reg) {                              \
                oa0[reg] *= alpha;                                            \
                oa1[reg] *= alpha;                                            \
            }                                                                 \
        }                                                                     \
        float lsum = 0.f;                                                     \
        _Pragma("unroll")                                                     \
        for (int reg = 0; reg < 16; ++reg) {                                  \
            p0[reg] = __expf(p0[reg] - mi);                                   \
            p1[reg] = __expf(p1[reg] - mi);                                   \
            lsum += p0[reg] + p1[reg];                                        \
        }                                                                     \
        li += lsum;                                                           \
        union { unsigned w[4]; bf16x8 v; } bq00, bq01, bq10, bq11;            \
        PACKP(p0, bq00, bq01);                                                \
        PACKP(p1, bq10, bq11);                                                \
        oa0 = __builtin_amdgcn_mfma_f32_32x32x16_bf16(vf00, bq00.v, oa0, 0, 0, 0); \
        oa1 = __builtin_amdgcn_mfma_f32_32x32x16_bf16(vf10, bq00.v, oa1, 0, 0, 0); \
        oa0 = __builtin_amdgcn_mfma_f32_32x32x16_bf16(vf01, bq01.v, oa0, 0, 0, 0); \
        oa1 = __builtin_amdgcn_mfma_f32_32x32x16_bf16(vf11, bq01.v, oa1, 0, 0, 0); \
        oa0 = __builtin_amdgcn_mfma_f32_32x32x16_bf16(vf02, bq10.v, oa0, 0, 0, 0); \
        oa1 = __builtin_amdgcn_mfma_f32_32x32x16_bf16(vf12, bq10.v, oa1, 0, 0, 0); \
        oa0 = __builtin_amdgcn_mfma_f32_32x32x16_bf16(vf03, bq11.v, oa0, 0, 0, 0); \
        oa1 = __builtin_amdgcn_mfma_f32_32x32x16_bf16(vf13, bq11.v, oa1, 0, 0, 0); \
    } while (0)

// grid (64 bh, 32 slices), block 256 = 4 waves. Slice s = 31 - blockIdx.y
// (longest first), queries q = 32s + l5, nt = s+1 tiles. Wave w owns chunk
// [w*nch, min(+nch, nt)) with nch = ceil(nt/4); own (mi,li,oacc). Waves 0-2
// post state to LDS; barrier; wave 3 merges + writes y.
__global__ __launch_bounds__(256) void attn_mfma(const unsigned short* __restrict__ qkvb,
                                                 const float* __restrict__ table,
                                                 unsigned short* __restrict__ y) {
    const int bh = blockIdx.x, b = bh >> 4, h = bh & 15;
    const int s = 31 - blockIdx.y;          // slice 31..0, longest first
    const int tid = threadIdx.x, lane = tid & 63, wave = tid >> 6;  // 0..3
    const int l5 = lane & 31, hi = lane >> 5, hi8 = hi * 8;

    __shared__ float tb[1152];
    __shared__ float mls[3][2][64];                                   // [wave][m|l][lane]
    __shared__ __attribute__((aligned(16))) float oas[3][64][32];     // [wave][lane][reg]

    const unsigned short* Qg  = qkvb + ((size_t)(b)*16 + h) * 65536;       // [t][d]
    const unsigned short* Kg  = qkvb + ((size_t)(4 + b)*16 + h) * 65536;   // [t][d]
    const unsigned short* Vtg = qkvb + ((size_t)(8 + b)*16 + h) * 65536;   // [d][t]

    const int qbase = 32 * s;
    const int q = qbase + l5;               // ONE query per lane (same all waves)
    const int nt = s + 1;                   // exact causal 32-j tile count
    const int nch = (nt + 3) >> 2;
    const int ks = wave * nch;
    const int kend = (ks + nch < nt) ? ks + nch : nt;

    // Q fragment (MFMA B-operand): B[col=q][k = t*16 + hi*8 + e]
    bf16x8 qf[4];
    {
        const unsigned short* qr = Qg + (size_t)q * 64 + hi8;
#pragma unroll
        for (int t = 0; t < 4; ++t) qf[t] = *(const bf16x8*)(qr + t * 16);
    }

    // tb[i] = table[(896+i)*16+h]; needed i = q-j+127 in [96, 32*s+158]
    const int tbn = 32 * s + 159;
    for (int i = tid; i < tbn; i += 256) tb[i] = table[(896 + i) * 16 + h];
    __syncthreads();  // tb ready

    f32x16 oa0 = {0.f}, oa1 = {0.f};  // O^T d-halves: row d, col q (own lane)
    float mi = -1e30f, li = 0.f;

    if (ks < kend) {
        bf16x8 kA[4], kB[4];
        LOADK(kA, ks);
        LOADK(kB, (kend - ks > 1) ? ks + 1 : ks);
        int kt = ks;
        for (; kt + 1 < kend; kt += 2) ATTN_TILE2(kt);
        if (kt < kend) ATTN_TILE(kA, kt);  // odd tail (kA prefetched in loop)
    }

    // merge 4 partial online-softmax states. m*/weights are partner-symmetric
    // (mi was always partner-max'd), so the final li partner-sum still works.
    if (wave < 3) {
        mls[wave][0][lane] = mi;
        mls[wave][1][lane] = li;
#pragma unroll
        for (int r = 0; r < 16; ++r) {
            oas[wave][lane][r] = oa0[r];
            oas[wave][lane][16 + r] = oa1[r];
        }
    }
    __syncthreads();
    if (wave == 3) {
        const float m0 = mls[0][0][lane], m1 = mls[1][0][lane], m2 = mls[2][0][lane];
        const float mstar = fmaxf(fmaxf(m0, m1), fmaxf(m2, mi));
        const float w0 = __expf(m0 - mstar), w1 = __expf(m1 - mstar);
        const float w2 = __expf(m2 - mstar), w3 = __expf(mi - mstar);
        float lm = w0 * mls[0][1][lane] + w1 * mls[1][1][lane] +
                   w2 * mls[2][1][lane] + w3 * li;
        f32x16 O0, O1;
#pragma unroll
        for (int r = 0; r < 16; ++r) {
            O0[r] = w0 * oas[0][lane][r] + w1 * oas[1][lane][r] +
                    w2 * oas[2][lane][r] + w3 * oa0[r];
            O1[r] = w0 * oas[0][lane][16 + r] + w1 * oas[1][lane][16 + r] +
                    w2 * oas[2][lane][16 + r] + w3 * oa1[r];
        }
        lm += __shfl_xor(lm, 32, 64);
        const float linv = 1.0f / lm;
        // lane's d = dh*32 + 8*g + 4*hi + (0..3)  (reg = 4g..4g+3 consecutive)
        unsigned short* yq = y + ((size_t)(b * 1024 + q)) * 1024 + h * 64;
#pragma unroll
        for (int g = 0; g < 4; ++g) {
            union { unsigned short u[4]; int2 v; } o4a, o4b;
#pragma unroll
            for (int i = 0; i < 4; ++i) {
                o4a.u[i] = f2bf(O0[4 * g + i] * linv);
                o4b.u[i] = f2bf(O1[4 * g + i] * linv);
            }
            *(int2*)(yq + 8 * g + 4 * hi) = o4a.v;
            *(int2*)(yq + 32 + 8 * g + 4 * hi) = o4b.v;
        }
    }
}

extern "C" void kernel_launch(void* const* d_in, const int* in_sizes, int n_in,
                              void* d_out, int out_size, void* d_ws, size_t ws_size,
                              hipStream_t stream) {
    const float* x      = (const float*)d_in[0];
    const float* qkv_w  = (const float*)d_in[1];
    const float* qkv_b  = (const float*)d_in[2];
    const float* proj_w = (const float*)d_in[3];
    const float* proj_b = (const float*)d_in[4];
    const float* rel    = (const float*)d_in[5];
    float* out = (float*)d_out;

    char* ws = (char*)d_ws;
    unsigned short* xb   = (unsigned short*)(ws + 0);
    unsigned short* qwb  = (unsigned short*)(ws + 8388608);
    unsigned short* pwb  = (unsigned short*)(ws + 14680064);
    float* table         = (float*)(ws + 16777216);
    unsigned short* qkvb = (unsigned short*)(ws + 16908288);
    unsigned short* yb   = (unsigned short*)(ws + 42074112);

    cvt3<<<4096, 256, 0, stream>>>(x, qkv_w, proj_w, xb, qwb, pwb);
    table_reduce<<<2047, 1024, 0, stream>>>(rel, table);
    gemm_bt<0><<<dim3(32, 24), 512, 0, stream>>>(xb, qwb, qkv_b, qkvb, nullptr,
                                                 4096, 3072, 1024);
    attn_mfma<<<dim3(64, 32), 256, 0, stream>>>(qkvb, table, yb);
    gemm_bt<1><<<dim3(32, 8), 512, 0, stream>>>(yb, pwb, proj_b, nullptr, out,
                                                4096, 1024, 1024);
}

// Round 14
// 211.250 us; speedup vs baseline: 1.0221x; 1.0221x over previous
//
#include <hip/hip_runtime.h>
#include <hip/hip_bf16.h>
#include <cstdint>

// Problem: B=4, T=1024, C=1024, H=16, D=64, MAX_LEN=1024, NPOS=2047
// Pipeline (R33):
//   cvt3: x, qkv_w, proj_w fp32 -> bf16 in ws (measured ~96% HBM peak: done)
//   table_reduce rel_pos_emb -> (2047,16)  [1-wave-per-head]
//   gemm_bt<0>: qkv = xb @ qwb^T + b -> scatter bf16; Q,K (B,H,T,D), V (B,H,D,T)
//   attn_mfma: 32x32 lane-local softmax, KVBLK=64 + defer-max, 4-way KV-SPLIT
//   gemm_bt<1>: out = y @ pwb^T + b -> fp32 d_out
//
// R29 measured: attn 41->62us REGRESSION, SQ_LDS_BANK_CONFLICT 0 -> 4.13M.
// Cause localized: merge buffer oas[wave][lane][reg] has lane-stride 128B ->
// 64-way bank conflict on all ~96 merge LDS ops/wave (~2016 events/block x
// 2048 blocks = the counter). kv-split itself untested, not refuted.
// R33 fixes (merge subsystem only; tile bodies/grid identical to R29):
//  1. oas -> [wave][reg][lane] lane-major: bank = lane%32, conflict-free.
//  2. parallel merge: ALL 4 waves post state; each wave merges reg-group
//     g=wave (8 of 32 regs) + writes its y slice -> no serial wave-3 tail.
// Falsifier: attn >= 41us with conflicts ~0 -> split is net-negative here;
// revert to R27 attn, pivot to gemm0.
//
// Workspace layout (bytes):
//   xb   @ 0         : 4096x1024 bf16  (8 MB)
//   qwb  @ 8388608   : 3072x1024 bf16  (6 MB)
//   pwb  @ 14680064  : 1024x1024 bf16  (2 MB)
//   table@ 16777216  : 2047x16 f32     (128 KB)
//   qkvb @ 16908288  : (3,4,16,64K) bf16 (24 MB)
//   y    @ 42074112  : 4096x1024 bf16  (8 MB)

typedef __bf16 bf16x8 __attribute__((ext_vector_type(8)));
typedef float f32x4 __attribute__((ext_vector_type(4)));
typedef float f32x16 __attribute__((ext_vector_type(16)));

__device__ __forceinline__ float bf2f(unsigned short u) {
    return __uint_as_float(((unsigned)u) << 16);
}
__device__ __forceinline__ unsigned short f2bf(float f) {
    __hip_bfloat16 h = __float2bfloat16(f);
    return *reinterpret_cast<unsigned short*>(&h);
}
__device__ __forceinline__ unsigned pk2(float a, float b) {
    return (unsigned)f2bf(a) | ((unsigned)f2bf(b) << 16);
}
__device__ __forceinline__ int4 cvt8(float4 a, float4 b) {
    union { unsigned short s[8]; int4 v; } u;
    u.s[0] = f2bf(a.x); u.s[1] = f2bf(a.y); u.s[2] = f2bf(a.z); u.s[3] = f2bf(a.w);
    u.s[4] = f2bf(b.x); u.s[5] = f2bf(b.y); u.s[6] = f2bf(b.z); u.s[7] = f2bf(b.w);
    return u.v;
}

// async global->LDS, 16B per lane. LDS dest must be linear base+lane*16.
__device__ __forceinline__ void gload16(const void* g, void* l) {
    __builtin_amdgcn_global_load_lds(
        reinterpret_cast<const __attribute__((address_space(1))) unsigned int*>(
            reinterpret_cast<uintptr_t>(g)),
        reinterpret_cast<__attribute__((address_space(3))) unsigned int*>(
            reinterpret_cast<uintptr_t>(l)),
        16, 0, 0);
}

// ---------------- fp32 -> bf16 one-shot convert (x, qkv_w, proj_w) ----------
__global__ __launch_bounds__(256) void cvt3(const float* __restrict__ x,
                                            const float* __restrict__ w1,
                                            const float* __restrict__ w2,
                                            unsigned short* __restrict__ ox,
                                            unsigned short* __restrict__ ow1,
                                            unsigned short* __restrict__ ow2) {
    const int i = blockIdx.x * 256 + threadIdx.x;
    const float* s; unsigned short* d; int li;
    if (i < 524288)      { s = x;  d = ox;  li = i; }
    else if (i < 917504) { s = w1; d = ow1; li = i - 524288; }
    else                 { s = w2; d = ow2; li = i - 917504; }
    const float4 a = *(const float4*)(s + (size_t)li * 8);
    const float4 b = *(const float4*)(s + (size_t)li * 8 + 4);
    *(int4*)(d + (size_t)li * 8) = cvt8(a, b);
}

// ---------------- rel_pos_emb (2047,1024) -> table (2047,16) ----------------
// 1024 thr = 16 waves; wave w sums head w's 64 d's: coalesced load + single
// 6-shfl tree.
__global__ __launch_bounds__(1024) void table_reduce(const float* __restrict__ rel,
                                                     float* __restrict__ table) {
    const int p = blockIdx.x;
    const int w = threadIdx.x >> 6, lane = threadIdx.x & 63;
    float v = rel[(size_t)p * 1024 + w * 64 + lane];
#pragma unroll
    for (int o = 32; o; o >>= 1) v += __shfl_xor(v, o, 64);
    if (lane == 0) table[p * 16 + w] = v;
}

// ---------------- bf16 MFMA GEMM: C = A B^T + bias (R12-exact) --------------
// 512 threads, 8 waves: wr=wave&1 (64-row half), wc=wave>>1 (32-col quarter).
// Staging: global_load_lds width=16; thread t covers row t>>2, shorts (t&3)*8
// -> LDS linear [128][32]. One call per matrix per K-step (8 KB each).
// EPI=0: scatter bf16 into qkv planes (Q,K [t][d], V [d][t]). EPI=1: fp32 out.
template <int EPI>
__global__ __launch_bounds__(512) void gemm_bt(const unsigned short* __restrict__ A,
                                               const unsigned short* __restrict__ B,
                                               const float* __restrict__ bias,
                                               unsigned short* __restrict__ outb,
                                               float* __restrict__ outf,
                                               int M, int N, int K) {
    __shared__ __attribute__((aligned(16))) unsigned short As[128 * 32];
    __shared__ __attribute__((aligned(16))) unsigned short Bs[128 * 32];
    const int bm = blockIdx.x * 128, bn = blockIdx.y * 128;
    const int tid = threadIdx.x, lane = tid & 63, wave = tid >> 6;
    const int wr = wave & 1, wc = wave >> 1;  // wc in 0..3
    const int quad = lane >> 4, lm = lane & 15;

    const int srow = tid >> 2;        // 0..127
    const int scol = (tid & 3) * 8;   // shorts
    const unsigned short* Ap = A + (size_t)(bm + srow) * K + scol;
    const unsigned short* Bp = B + (size_t)(bn + srow) * K + scol;
    unsigned short* AsW = &As[tid * 8];   // == row srow, col scol (linear)
    unsigned short* BsW = &Bs[tid * 8];

    f32x4 acc[4][2];
#pragma unroll
    for (int r = 0; r < 4; ++r)
#pragma unroll
        for (int c = 0; c < 2; ++c) acc[r][c] = (f32x4){0.f, 0.f, 0.f, 0.f};

    for (int kk = 0; kk < K; kk += 32) {
        gload16(Ap + kk, AsW);
        gload16(Bp + kk, BsW);
        __syncthreads();  // compiler emits vmcnt(0) drain before s_barrier

        bf16x8 af[4], bfr[2];
#pragma unroll
        for (int r = 0; r < 4; ++r)
            af[r] = *(const bf16x8*)(&As[(64 * wr + 16 * r + lm) * 32 + quad * 8]);
#pragma unroll
        for (int c = 0; c < 2; ++c)
            bfr[c] = *(const bf16x8*)(&Bs[(32 * wc + 16 * c + lm) * 32 + quad * 8]);
#pragma unroll
        for (int r = 0; r < 4; ++r)
#pragma unroll
            for (int c = 0; c < 2; ++c)
                acc[r][c] = __builtin_amdgcn_mfma_f32_16x16x32_bf16(af[r], bfr[c], acc[r][c], 0, 0, 0);
        __syncthreads();
    }

    // C/D layout: col = lane&15, row = (lane>>4)*4 + reg
#pragma unroll
    for (int r = 0; r < 4; ++r)
#pragma unroll
        for (int c = 0; c < 2; ++c)
#pragma unroll
            for (int i = 0; i < 4; ++i) {
                const int row = bm + 64 * wr + 16 * r + quad * 4 + i;
                const int col = bn + 32 * wc + 16 * c + lm;
                const float v = acc[r][c][i] + bias[col];
                if (EPI == 0) {
                    const int b = row >> 10, t = row & 1023;
                    const int s3 = col >> 10, rem = col & 1023;
                    const int h = rem >> 6, d = rem & 63;
                    const size_t base = (((size_t)s3 * 4 + b) * 16 + h) * 65536;
                    const size_t off = base + (s3 == 2 ? (size_t)d * 1024 + t
                                                       : (size_t)t * 64 + d);
                    outb[off] = f2bf(v);
                } else {
                    outf[(size_t)row * N + col] = v;
                }
            }
}

// ---------------- MFMA flash causal attention (4-way kv-split) -------------
// 32x32 lane-local softmax, KVBLK=64 joint tiles + T13 defer-max.
#define LOADK(DST, KT)                                                        \
    do {                                                                      \
        const unsigned short* kr_ = Kg + (size_t)((KT) * 32 + l5) * 64 + hi8; \
        DST[0] = *(const bf16x8*)(kr_);                                       \
        DST[1] = *(const bf16x8*)(kr_ + 16);                                  \
        DST[2] = *(const bf16x8*)(kr_ + 32);                                  \
        DST[3] = *(const bf16x8*)(kr_ + 48);                                  \
    } while (0)

// Single 32-j tile (tail only; always-rescale path). Uses kA-style frag KF.
#define ATTN_TILE(KF, KT)                                                     \
    do {                                                                      \
        const int jb = (KT) * 32;                                             \
        const unsigned short* vb_ = Vtg + (size_t)l5 * 1024 + jb + hi8;       \
        const bf16x8 vf00 = *(const bf16x8*)(vb_);                            \
        const bf16x8 vf01 = *(const bf16x8*)(vb_ + 16);                       \
        const bf16x8 vf10 = *(const bf16x8*)(vb_ + 32768);                    \
        const bf16x8 vf11 = *(const bf16x8*)(vb_ + 32768 + 16);               \
        f32x16 s = {0.f};                                                     \
        _Pragma("unroll")                                                     \
        for (int t = 0; t < 4; ++t)                                           \
            s = __builtin_amdgcn_mfma_f32_32x32x16_bf16(KF[t], qf[t], s, 0, 0, 0); \
        float p[16];                                                          \
        _Pragma("unroll")                                                     \
        for (int reg = 0; reg < 16; ++reg) {                                  \
            const int j = jb + (reg & 3) + 8 * (reg >> 2) + 4 * hi;           \
            p[reg] = fmaf(s[reg], 0.125f, tb[q - j + 127]);                   \
        }                                                                     \
        if (jb + 31 > qbase) {                                                \
            _Pragma("unroll")                                                 \
            for (int reg = 0; reg < 16; ++reg) {                              \
                const int j = jb + (reg & 3) + 8 * (reg >> 2) + 4 * hi;       \
                p[reg] = (j <= q) ? p[reg] : -1e30f;                          \
            }                                                                 \
        }                                                                     \
        float mx = p[0];                                                      \
        _Pragma("unroll")                                                     \
        for (int reg = 1; reg < 16; ++reg) mx = fmaxf(mx, p[reg]);            \
        mx = fmaxf(mx, __shfl_xor(mx, 32, 64));                               \
        if (!__all(mx <= mi + 8.f)) {                                         \
            const float mnew = fmaxf(mi, mx);                                 \
            const float alpha = __expf(mi - mnew);                            \
            mi = mnew;                                                        \
            li *= alpha;                                                      \
            _Pragma("unroll")                                                 \
            for (int reg = 0; reg < 16; ++reg) {                              \
                oa0[reg] *= alpha;                                            \
                oa1[reg] *= alpha;                                            \
            }                                                                 \
        }                                                                     \
        float lsum = 0.f;                                                     \
        _Pragma("unroll")                                                     \
        for (int reg = 0; reg < 16; ++reg) {                                  \
            p[reg] = __expf(p[reg] - mi);                                     \
            lsum += p[reg];                                                   \
        }                                                                     \
        li += lsum;                                                           \
        const unsigned P0 = pk2(p[0], p[1]),   P1 = pk2(p[2], p[3]);          \
        const unsigned P2 = pk2(p[4], p[5]),   P3 = pk2(p[6], p[7]);          \
        const unsigned P4 = pk2(p[8], p[9]),   P5 = pk2(p[10], p[11]);        \
        const unsigned P6 = pk2(p[12], p[13]), P7 = pk2(p[14], p[15]);        \
        const unsigned R0 = __shfl_xor(hi ? P0 : P2, 32, 64);                 \
        const unsigned R1 = __shfl_xor(hi ? P1 : P3, 32, 64);                 \
        const unsigned R2 = __shfl_xor(hi ? P4 : P6, 32, 64);                 \
        const unsigned R3 = __shfl_xor(hi ? P5 : P7, 32, 64);                 \
        union { unsigned w[4]; bf16x8 v; } bq0, bq1;                          \
        bq0.w[0] = hi ? R0 : P0;  bq0.w[1] = hi ? R1 : P1;                    \
        bq0.w[2] = hi ? P2 : R0;  bq0.w[3] = hi ? P3 : R1;                    \
        bq1.w[0] = hi ? R2 : P4;  bq1.w[1] = hi ? R3 : P5;                    \
        bq1.w[2] = hi ? P6 : R2;  bq1.w[3] = hi ? P7 : R3;                    \
        oa0 = __builtin_amdgcn_mfma_f32_32x32x16_bf16(vf00, bq0.v, oa0, 0, 0, 0); \
        oa0 = __builtin_amdgcn_mfma_f32_32x32x16_bf16(vf01, bq1.v, oa0, 0, 0, 0); \
        oa1 = __builtin_amdgcn_mfma_f32_32x32x16_bf16(vf10, bq0.v, oa1, 0, 0, 0); \
        oa1 = __builtin_amdgcn_mfma_f32_32x32x16_bf16(vf11, bq1.v, oa1, 0, 0, 0); \
    } while (0)

// Pack+partner-exchange p[16] -> two PV B-frags (BQA, BQB).
#define PACKP(p, BQA, BQB)                                                    \
    do {                                                                      \
        const unsigned P0 = pk2(p[0], p[1]),   P1 = pk2(p[2], p[3]);          \
        const unsigned P2 = pk2(p[4], p[5]),   P3 = pk2(p[6], p[7]);          \
        const unsigned P4 = pk2(p[8], p[9]),   P5 = pk2(p[10], p[11]);        \
        const unsigned P6 = pk2(p[12], p[13]), P7 = pk2(p[14], p[15]);        \
        const unsigned R0 = __shfl_xor(hi ? P0 : P2, 32, 64);                 \
        const unsigned R1 = __shfl_xor(hi ? P1 : P3, 32, 64);                 \
        const unsigned R2 = __shfl_xor(hi ? P4 : P6, 32, 64);                 \
        const unsigned R3 = __shfl_xor(hi ? P5 : P7, 32, 64);                 \
        BQA.w[0] = hi ? R0 : P0;  BQA.w[1] = hi ? R1 : P1;                    \
        BQA.w[2] = hi ? P2 : R0;  BQA.w[3] = hi ? P3 : R1;                    \
        BQB.w[0] = hi ? R2 : P4;  BQB.w[1] = hi ? R3 : P5;                    \
        BQB.w[2] = hi ? P6 : R2;  BQB.w[3] = hi ? P7 : R3;                    \
    } while (0)

// Joint KVBLK=64: subtiles KT (kA) and KT+1 (kB); ONE softmax update.
// Prefetch bounded by kend (wave's chunk end).
#define ATTN_TILE2(KT)                                                        \
    do {                                                                      \
        const int jb = (KT) * 32;                                             \
        const unsigned short* vb_ = Vtg + (size_t)l5 * 1024 + jb + hi8;       \
        const bf16x8 vf00 = *(const bf16x8*)(vb_);                            \
        const bf16x8 vf01 = *(const bf16x8*)(vb_ + 16);                       \
        const bf16x8 vf02 = *(const bf16x8*)(vb_ + 32);                       \
        const bf16x8 vf03 = *(const bf16x8*)(vb_ + 48);                       \
        const bf16x8 vf10 = *(const bf16x8*)(vb_ + 32768);                    \
        const bf16x8 vf11 = *(const bf16x8*)(vb_ + 32768 + 16);               \
        const bf16x8 vf12 = *(const bf16x8*)(vb_ + 32768 + 32);               \
        const bf16x8 vf13 = *(const bf16x8*)(vb_ + 32768 + 48);               \
        f32x16 s0v = {0.f}, s1v = {0.f};                                      \
        _Pragma("unroll")                                                     \
        for (int t = 0; t < 4; ++t) {                                         \
            s0v = __builtin_amdgcn_mfma_f32_32x32x16_bf16(kA[t], qf[t], s0v, 0, 0, 0); \
            s1v = __builtin_amdgcn_mfma_f32_32x32x16_bf16(kB[t], qf[t], s1v, 0, 0, 0); \
        }                                                                     \
        if ((KT) + 2 < kend) LOADK(kA, (KT) + 2);                             \
        if ((KT) + 3 < kend) LOADK(kB, (KT) + 3);                             \
        float p0[16], p1[16];                                                 \
        _Pragma("unroll")                                                     \
        for (int reg = 0; reg < 16; ++reg) {                                  \
            const int jo = (reg & 3) + 8 * (reg >> 2) + 4 * hi;               \
            p0[reg] = fmaf(s0v[reg], 0.125f, tb[q - jb - jo + 127]);          \
            p1[reg] = fmaf(s1v[reg], 0.125f, tb[q - jb - 32 - jo + 127]);     \
        }                                                                     \
        if (jb + 63 > qbase) {                                                \
            _Pragma("unroll")                                                 \
            for (int reg = 0; reg < 16; ++reg) {                              \
                const int jo = (reg & 3) + 8 * (reg >> 2) + 4 * hi;           \
                p0[reg] = (jb + jo <= q) ? p0[reg] : -1e30f;                  \
                p1[reg] = (jb + 32 + jo <= q) ? p1[reg] : -1e30f;             \
            }                                                                 \
        }                                                                     \
        float mx = p0[0];                                                     \
        _Pragma("unroll")                                                     \
        for (int reg = 1; reg < 16; ++reg) mx = fmaxf(mx, p0[reg]);           \
        _Pragma("unroll")                                                     \
        for (int reg = 0; reg < 16; ++reg) mx = fmaxf(mx, p1[reg]);           \
        mx = fmaxf(mx, __shfl_xor(mx, 32, 64));                               \
        if (!__all(mx <= mi + 8.f)) {                                         \
            const float mnew = fmaxf(mi, mx);                                 \
            const float alpha = __expf(mi - mnew);                            \
            mi = mnew;                                                        \
            li *= alpha;                                                      \
            _Pragma("unroll")                                                 \
            for (int reg = 0; reg < 16; ++reg) {                              \
                oa0[reg] *= alpha;                                            \
                oa1[reg] *= alpha;                                            \
            }                                                                 \
        }                                                                     \
        float lsum = 0.f;                                                     \
        _Pragma("unroll")                                                     \
        for (int reg = 0; reg < 16; ++reg) {                                  \
            p0[reg] = __expf(p0[reg] - mi);                                   \
            p1[reg] = __expf(p1[reg] - mi);                                   \
            lsum += p0[reg] + p1[reg];                                        \
        }                                                                     \
        li += lsum;                                                           \
        union { unsigned w[4]; bf16x8 v; } bq00, bq01, bq10, bq11;            \
        PACKP(p0, bq00, bq01);                                                \
        PACKP(p1, bq10, bq11);                                                \
        oa0 = __builtin_amdgcn_mfma_f32_32x32x16_bf16(vf00, bq00.v, oa0, 0, 0, 0); \
        oa1 = __builtin_amdgcn_mfma_f32_32x32x16_bf16(vf10, bq00.v, oa1, 0, 0, 0); \
        oa0 = __builtin_amdgcn_mfma_f32_32x32x16_bf16(vf01, bq01.v, oa0, 0, 0, 0); \
        oa1 = __builtin_amdgcn_mfma_f32_32x32x16_bf16(vf11, bq01.v, oa1, 0, 0, 0); \
        oa0 = __builtin_amdgcn_mfma_f32_32x32x16_bf16(vf02, bq10.v, oa0, 0, 0, 0); \
        oa1 = __builtin_amdgcn_mfma_f32_32x32x16_bf16(vf12, bq10.v, oa1, 0, 0, 0); \
        oa0 = __builtin_amdgcn_mfma_f32_32x32x16_bf16(vf03, bq11.v, oa0, 0, 0, 0); \
        oa1 = __builtin_amdgcn_mfma_f32_32x32x16_bf16(vf13, bq11.v, oa1, 0, 0, 0); \
    } while (0)

// grid (64 bh, 32 slices), block 256 = 4 waves. Slice s = 31 - blockIdx.y
// (longest first), queries q = 32s + l5, nt = s+1 tiles. Wave w owns chunk
// [w*nch, min(+nch, nt)) with nch = ceil(nt/4); own (mi,li,oacc). ALL waves
// post state to lane-major LDS; barrier; wave w merges reg-group g=w and
// writes its y slice (parallel merge, conflict-free).
__global__ __launch_bounds__(256) void attn_mfma(const unsigned short* __restrict__ qkvb,
                                                 const float* __restrict__ table,
                                                 unsigned short* __restrict__ y) {
    const int bh = blockIdx.x, b = bh >> 4, h = bh & 15;
    const int s = 31 - blockIdx.y;          // slice 31..0, longest first
    const int tid = threadIdx.x, lane = tid & 63, wave = tid >> 6;  // 0..3
    const int l5 = lane & 31, hi = lane >> 5, hi8 = hi * 8;

    __shared__ float tb[1152];
    __shared__ float mls[4][2][64];                                   // [wave][m|l][lane]
    __shared__ __attribute__((aligned(16))) float oas[4][32][64];     // [wave][reg][lane]

    const unsigned short* Qg  = qkvb + ((size_t)(b)*16 + h) * 65536;       // [t][d]
    const unsigned short* Kg  = qkvb + ((size_t)(4 + b)*16 + h) * 65536;   // [t][d]
    const unsigned short* Vtg = qkvb + ((size_t)(8 + b)*16 + h) * 65536;   // [d][t]

    const int qbase = 32 * s;
    const int q = qbase + l5;               // ONE query per lane (same all waves)
    const int nt = s + 1;                   // exact causal 32-j tile count
    const int nch = (nt + 3) >> 2;
    const int ks = wave * nch;
    const int kend = (ks + nch < nt) ? ks + nch : nt;

    // Q fragment (MFMA B-operand): B[col=q][k = t*16 + hi*8 + e]
    bf16x8 qf[4];
    {
        const unsigned short* qr = Qg + (size_t)q * 64 + hi8;
#pragma unroll
        for (int t = 0; t < 4; ++t) qf[t] = *(const bf16x8*)(qr + t * 16);
    }

    // tb[i] = table[(896+i)*16+h]; needed i = q-j+127 in [96, 32*s+158]
    const int tbn = 32 * s + 159;
    for (int i = tid; i < tbn; i += 256) tb[i] = table[(896 + i) * 16 + h];
    __syncthreads();  // tb ready

    f32x16 oa0 = {0.f}, oa1 = {0.f};  // O^T d-halves: row d, col q (own lane)
    float mi = -1e30f, li = 0.f;

    if (ks < kend) {
        bf16x8 kA[4], kB[4];
        LOADK(kA, ks);
        LOADK(kB, (kend - ks > 1) ? ks + 1 : ks);
        int kt = ks;
        for (; kt + 1 < kend; kt += 2) ATTN_TILE2(kt);
        if (kt < kend) ATTN_TILE(kA, kt);  // odd tail (kA prefetched in loop)
    }

    // ALL waves post state; lane-major -> bank = lane%32, conflict-free.
    mls[wave][0][lane] = mi;
    mls[wave][1][lane] = li;
#pragma unroll
    for (int r = 0; r < 16; ++r) {
        oas[wave][r][lane] = oa0[r];
        oas[wave][16 + r][lane] = oa1[r];
    }
    __syncthreads();

    // parallel merge: wave w = reg-group g=w of both d-halves. Weights are
    // partner-symmetric (mi always partner-max'd) -> final li partner-sum OK.
    const float m0 = mls[0][0][lane], m1 = mls[1][0][lane];
    const float m2 = mls[2][0][lane], m3 = mls[3][0][lane];
    const float mstar = fmaxf(fmaxf(m0, m1), fmaxf(m2, m3));
    const float w0 = __expf(m0 - mstar), w1 = __expf(m1 - mstar);
    const float w2 = __expf(m2 - mstar), w3 = __expf(m3 - mstar);
    float lm = w0 * mls[0][1][lane] + w1 * mls[1][1][lane] +
               w2 * mls[2][1][lane] + w3 * mls[3][1][lane];
    lm += __shfl_xor(lm, 32, 64);
    const float linv = 1.0f / lm;
    // lane's d = dh*32 + 8*g + 4*hi + (0..3) with g = wave
    unsigned short* yq = y + ((size_t)(b * 1024 + q)) * 1024 + h * 64;
    {
        const int g = wave;
        union { unsigned short u[4]; int2 v; } o4a, o4b;
#pragma unroll
        for (int i = 0; i < 4; ++i) {
            const int r0 = 4 * g + i, r1 = 16 + 4 * g + i;
            const float v0 = w0 * oas[0][r0][lane] + w1 * oas[1][r0][lane] +
                             w2 * oas[2][r0][lane] + w3 * oas[3][r0][lane];
            const float v1 = w0 * oas[0][r1][lane] + w1 * oas[1][r1][lane] +
                             w2 * oas[2][r1][lane] + w3 * oas[3][r1][lane];
            o4a.u[i] = f2bf(v0 * linv);
            o4b.u[i] = f2bf(v1 * linv);
        }
        *(int2*)(yq + 8 * g + 4 * hi) = o4a.v;
        *(int2*)(yq + 32 + 8 * g + 4 * hi) = o4b.v;
    }
}

extern "C" void kernel_launch(void* const* d_in, const int* in_sizes, int n_in,
                              void* d_out, int out_size, void* d_ws, size_t ws_size,
                              hipStream_t stream) {
    const float* x      = (const float*)d_in[0];
    const float* qkv_w  = (const float*)d_in[1];
    const float* qkv_b  = (const float*)d_in[2];
    const float* proj_w = (const float*)d_in[3];
    const float* proj_b = (const float*)d_in[4];
    const float* rel    = (const float*)d_in[5];
    float* out = (float*)d_out;

    char* ws = (char*)d_ws;
    unsigned short* xb   = (unsigned short*)(ws + 0);
    unsigned short* qwb  = (unsigned short*)(ws + 8388608);
    unsigned short* pwb  = (unsigned short*)(ws + 14680064);
    float* table         = (float*)(ws + 16777216);
    unsigned short* qkvb = (unsigned short*)(ws + 16908288);
    unsigned short* yb   = (unsigned short*)(ws + 42074112);

    cvt3<<<4096, 256, 0, stream>>>(x, qkv_w, proj_w, xb, qwb, pwb);
    table_reduce<<<2047, 1024, 0, stream>>>(rel, table);
    gemm_bt<0><<<dim3(32, 24), 512, 0, stream>>>(xb, qwb, qkv_b, qkvb, nullptr,
                                                 4096, 3072, 1024);
    attn_mfma<<<dim3(64, 32), 256, 0, stream>>>(qkvb, table, yb);
    gemm_bt<1><<<dim3(32, 8), 512, 0, stream>>>(yb, pwb, proj_b, nullptr, out,
                                                4096, 1024, 1024);
}

// Round 15
// 194.666 us; speedup vs baseline: 1.1092x; 1.0852x over previous
//
#include <hip/hip_runtime.h>
#include <hip/hip_bf16.h>
#include <cstdint>

// Problem: B=4, T=1024, C=1024, H=16, D=64, MAX_LEN=1024, NPOS=2047
// Pipeline (R35):
//   cvt3: x, qkv_w, proj_w fp32 -> bf16 in ws (measured ~96% HBM peak: done)
//   table_reduce rel_pos_emb -> (2047,16)  [1-wave-per-head]
//   gemm_bt<0>: qkv = xb @ qwb^T + b -> scatter bf16; Q,K (B,H,T,D), V (B,H,D,T)
//   attn_mfma: flash causal, 32x32 lane-local softmax, KVBLK=64 + defer-max
//   gemm_bt<1>: out = y @ pwb^T + b -> fp32 d_out
//
// R33 post-mortem: merge bank conflicts 4.13M -> 0 (lane-major fix worked)
// but attn 58.4us >= 41us falsifier -> kv-split NET-NEGATIVE at this shape
// (occ stuck 10%: VGPR 148 + 39KB LDS + per-block fixed costs ate the TLP).
// R35: (1) attn REVERTED to R27-exact (grid (64,16), 128thr/2 waves, nt =
// 2*level+wave+1; measured ~41us in the 193.2 best). (2) gemm_bt gets
// __launch_bounds__(512, 5): R27 counters show VGPR_Count=32 (minimal-reg
// schedule serializes the 6 ds_read->MFMA chains; rule-19 lottery); R12
// measured the SAME source at VGPR 88 / occ 74.8% / 38.5us. Cap 512/5~=102
// gives the allocator room for the 88-reg schedule without the squeeze.
//
// Workspace layout (bytes):
//   xb   @ 0         : 4096x1024 bf16  (8 MB)
//   qwb  @ 8388608   : 3072x1024 bf16  (6 MB)
//   pwb  @ 14680064  : 1024x1024 bf16  (2 MB)
//   table@ 16777216  : 2047x16 f32     (128 KB)
//   qkvb @ 16908288  : (3,4,16,64K) bf16 (24 MB)
//   y    @ 42074112  : 4096x1024 bf16  (8 MB)

typedef __bf16 bf16x8 __attribute__((ext_vector_type(8)));
typedef float f32x4 __attribute__((ext_vector_type(4)));
typedef float f32x16 __attribute__((ext_vector_type(16)));

__device__ __forceinline__ float bf2f(unsigned short u) {
    return __uint_as_float(((unsigned)u) << 16);
}
__device__ __forceinline__ unsigned short f2bf(float f) {
    __hip_bfloat16 h = __float2bfloat16(f);
    return *reinterpret_cast<unsigned short*>(&h);
}
__device__ __forceinline__ unsigned pk2(float a, float b) {
    return (unsigned)f2bf(a) | ((unsigned)f2bf(b) << 16);
}
__device__ __forceinline__ int4 cvt8(float4 a, float4 b) {
    union { unsigned short s[8]; int4 v; } u;
    u.s[0] = f2bf(a.x); u.s[1] = f2bf(a.y); u.s[2] = f2bf(a.z); u.s[3] = f2bf(a.w);
    u.s[4] = f2bf(b.x); u.s[5] = f2bf(b.y); u.s[6] = f2bf(b.z); u.s[7] = f2bf(b.w);
    return u.v;
}

// async global->LDS, 16B per lane. LDS dest must be linear base+lane*16.
__device__ __forceinline__ void gload16(const void* g, void* l) {
    __builtin_amdgcn_global_load_lds(
        reinterpret_cast<const __attribute__((address_space(1))) unsigned int*>(
            reinterpret_cast<uintptr_t>(g)),
        reinterpret_cast<__attribute__((address_space(3))) unsigned int*>(
            reinterpret_cast<uintptr_t>(l)),
        16, 0, 0);
}

// ---------------- fp32 -> bf16 one-shot convert (x, qkv_w, proj_w) ----------
__global__ __launch_bounds__(256) void cvt3(const float* __restrict__ x,
                                            const float* __restrict__ w1,
                                            const float* __restrict__ w2,
                                            unsigned short* __restrict__ ox,
                                            unsigned short* __restrict__ ow1,
                                            unsigned short* __restrict__ ow2) {
    const int i = blockIdx.x * 256 + threadIdx.x;
    const float* s; unsigned short* d; int li;
    if (i < 524288)      { s = x;  d = ox;  li = i; }
    else if (i < 917504) { s = w1; d = ow1; li = i - 524288; }
    else                 { s = w2; d = ow2; li = i - 917504; }
    const float4 a = *(const float4*)(s + (size_t)li * 8);
    const float4 b = *(const float4*)(s + (size_t)li * 8 + 4);
    *(int4*)(d + (size_t)li * 8) = cvt8(a, b);
}

// ---------------- rel_pos_emb (2047,1024) -> table (2047,16) ----------------
// 1024 thr = 16 waves; wave w sums head w's 64 d's: coalesced load + single
// 6-shfl tree.
__global__ __launch_bounds__(1024) void table_reduce(const float* __restrict__ rel,
                                                     float* __restrict__ table) {
    const int p = blockIdx.x;
    const int w = threadIdx.x >> 6, lane = threadIdx.x & 63;
    float v = rel[(size_t)p * 1024 + w * 64 + lane];
#pragma unroll
    for (int o = 32; o; o >>= 1) v += __shfl_xor(v, o, 64);
    if (lane == 0) table[p * 16 + w] = v;
}

// ---------------- bf16 MFMA GEMM: C = A B^T + bias (R12 + LB(512,5)) --------
// 512 threads, 8 waves: wr=wave&1 (64-row half), wc=wave>>1 (32-col quarter).
// Staging: global_load_lds width=16; thread t covers row t>>2, shorts (t&3)*8
// -> LDS linear [128][32]. One call per matrix per K-step (8 KB each).
// __launch_bounds__(512,5): VGPR cap ~102 -- room for R12's 88-reg schedule
// (frag ILP), forbids both the 32-reg squeeze and a >102 blowup.
// EPI=0: scatter bf16 into qkv planes (Q,K [t][d], V [d][t]). EPI=1: fp32 out.
template <int EPI>
__global__ __launch_bounds__(512, 5) void gemm_bt(const unsigned short* __restrict__ A,
                                                  const unsigned short* __restrict__ B,
                                                  const float* __restrict__ bias,
                                                  unsigned short* __restrict__ outb,
                                                  float* __restrict__ outf,
                                                  int M, int N, int K) {
    __shared__ __attribute__((aligned(16))) unsigned short As[128 * 32];
    __shared__ __attribute__((aligned(16))) unsigned short Bs[128 * 32];
    const int bm = blockIdx.x * 128, bn = blockIdx.y * 128;
    const int tid = threadIdx.x, lane = tid & 63, wave = tid >> 6;
    const int wr = wave & 1, wc = wave >> 1;  // wc in 0..3
    const int quad = lane >> 4, lm = lane & 15;

    const int srow = tid >> 2;        // 0..127
    const int scol = (tid & 3) * 8;   // shorts
    const unsigned short* Ap = A + (size_t)(bm + srow) * K + scol;
    const unsigned short* Bp = B + (size_t)(bn + srow) * K + scol;
    unsigned short* AsW = &As[tid * 8];   // == row srow, col scol (linear)
    unsigned short* BsW = &Bs[tid * 8];

    f32x4 acc[4][2];
#pragma unroll
    for (int r = 0; r < 4; ++r)
#pragma unroll
        for (int c = 0; c < 2; ++c) acc[r][c] = (f32x4){0.f, 0.f, 0.f, 0.f};

    for (int kk = 0; kk < K; kk += 32) {
        gload16(Ap + kk, AsW);
        gload16(Bp + kk, BsW);
        __syncthreads();  // compiler emits vmcnt(0) drain before s_barrier

        bf16x8 af[4], bfr[2];
#pragma unroll
        for (int r = 0; r < 4; ++r)
            af[r] = *(const bf16x8*)(&As[(64 * wr + 16 * r + lm) * 32 + quad * 8]);
#pragma unroll
        for (int c = 0; c < 2; ++c)
            bfr[c] = *(const bf16x8*)(&Bs[(32 * wc + 16 * c + lm) * 32 + quad * 8]);
#pragma unroll
        for (int r = 0; r < 4; ++r)
#pragma unroll
            for (int c = 0; c < 2; ++c)
                acc[r][c] = __builtin_amdgcn_mfma_f32_16x16x32_bf16(af[r], bfr[c], acc[r][c], 0, 0, 0);
        __syncthreads();
    }

    // C/D layout: col = lane&15, row = (lane>>4)*4 + reg
#pragma unroll
    for (int r = 0; r < 4; ++r)
#pragma unroll
        for (int c = 0; c < 2; ++c)
#pragma unroll
            for (int i = 0; i < 4; ++i) {
                const int row = bm + 64 * wr + 16 * r + quad * 4 + i;
                const int col = bn + 32 * wc + 16 * c + lm;
                const float v = acc[r][c][i] + bias[col];
                if (EPI == 0) {
                    const int b = row >> 10, t = row & 1023;
                    const int s3 = col >> 10, rem = col & 1023;
                    const int h = rem >> 6, d = rem & 63;
                    const size_t base = (((size_t)s3 * 4 + b) * 16 + h) * 65536;
                    const size_t off = base + (s3 == 2 ? (size_t)d * 1024 + t
                                                       : (size_t)t * 64 + d);
                    outb[off] = f2bf(v);
                } else {
                    outf[(size_t)row * N + col] = v;
                }
            }
}

// ---------------- MFMA flash causal attention (R27-exact) ------------------
// 32x32 lane-local softmax, KVBLK=64 joint tiles + T13 defer-max.
#define LOADK(DST, KT)                                                        \
    do {                                                                      \
        const unsigned short* kr_ = Kg + (size_t)((KT) * 32 + l5) * 64 + hi8; \
        DST[0] = *(const bf16x8*)(kr_);                                       \
        DST[1] = *(const bf16x8*)(kr_ + 16);                                  \
        DST[2] = *(const bf16x8*)(kr_ + 32);                                  \
        DST[3] = *(const bf16x8*)(kr_ + 48);                                  \
    } while (0)

// Single 32-j tile (tail only; always-rescale path). Uses kA-style frag KF.
#define ATTN_TILE(KF, KT)                                                     \
    do {                                                                      \
        const int jb = (KT) * 32;                                             \
        const unsigned short* vb_ = Vtg + (size_t)l5 * 1024 + jb + hi8;       \
        const bf16x8 vf00 = *(const bf16x8*)(vb_);                            \
        const bf16x8 vf01 = *(const bf16x8*)(vb_ + 16);                       \
        const bf16x8 vf10 = *(const bf16x8*)(vb_ + 32768);                    \
        const bf16x8 vf11 = *(const bf16x8*)(vb_ + 32768 + 16);               \
        f32x16 s = {0.f};                                                     \
        _Pragma("unroll")                                                     \
        for (int t = 0; t < 4; ++t)                                           \
            s = __builtin_amdgcn_mfma_f32_32x32x16_bf16(KF[t], qf[t], s, 0, 0, 0); \
        float p[16];                                                          \
        _Pragma("unroll")                                                     \
        for (int reg = 0; reg < 16; ++reg) {                                  \
            const int j = jb + (reg & 3) + 8 * (reg >> 2) + 4 * hi;           \
            p[reg] = fmaf(s[reg], 0.125f, tb[q - j + 127]);                   \
        }                                                                     \
        if (jb + 31 > qbase) {                                                \
            _Pragma("unroll")                                                 \
            for (int reg = 0; reg < 16; ++reg) {                              \
                const int j = jb + (reg & 3) + 8 * (reg >> 2) + 4 * hi;       \
                p[reg] = (j <= q) ? p[reg] : -1e30f;                          \
            }                                                                 \
        }                                                                     \
        float mx = p[0];                                                      \
        _Pragma("unroll")                                                     \
        for (int reg = 1; reg < 16; ++reg) mx = fmaxf(mx, p[reg]);            \
        mx = fmaxf(mx, __shfl_xor(mx, 32, 64));                               \
        if (!__all(mx <= mi + 8.f)) {                                         \
            const float mnew = fmaxf(mi, mx);                                 \
            const float alpha = __expf(mi - mnew);                            \
            mi = mnew;                                                        \
            li *= alpha;                                                      \
            _Pragma("unroll")                                                 \
            for (int reg = 0; reg < 16; ++reg) {                              \
                oa0[reg] *= alpha;                                            \
                oa1[reg] *= alpha;                                            \
            }                                                                 \
        }                                                                     \
        float lsum = 0.f;                                                     \
        _Pragma("unroll")                                                     \
        for (int reg = 0; reg < 16; ++reg) {                                  \
            p[reg] = __expf(p[reg] - mi);                                     \
            lsum += p[reg];                                                   \
        }                                                                     \
        li += lsum;                                                           \
        const unsigned P0 = pk2(p[0], p[1]),   P1 = pk2(p[2], p[3]);          \
        const unsigned P2 = pk2(p[4], p[5]),   P3 = pk2(p[6], p[7]);          \
        const unsigned P4 = pk2(p[8], p[9]),   P5 = pk2(p[10], p[11]);        \
        const unsigned P6 = pk2(p[12], p[13]), P7 = pk2(p[14], p[15]);        \
        const unsigned R0 = __shfl_xor(hi ? P0 : P2, 32, 64);                 \
        const unsigned R1 = __shfl_xor(hi ? P1 : P3, 32, 64);                 \
        const unsigned R2 = __shfl_xor(hi ? P4 : P6, 32, 64);                 \
        const unsigned R3 = __shfl_xor(hi ? P5 : P7, 32, 64);                 \
        union { unsigned w[4]; bf16x8 v; } bq0, bq1;                          \
        bq0.w[0] = hi ? R0 : P0;  bq0.w[1] = hi ? R1 : P1;                    \
        bq0.w[2] = hi ? P2 : R0;  bq0.w[3] = hi ? P3 : R1;                    \
        bq1.w[0] = hi ? R2 : P4;  bq1.w[1] = hi ? R3 : P5;                    \
        bq1.w[2] = hi ? P6 : R2;  bq1.w[3] = hi ? P7 : R3;                    \
        oa0 = __builtin_amdgcn_mfma_f32_32x32x16_bf16(vf00, bq0.v, oa0, 0, 0, 0); \
        oa0 = __builtin_amdgcn_mfma_f32_32x32x16_bf16(vf01, bq1.v, oa0, 0, 0, 0); \
        oa1 = __builtin_amdgcn_mfma_f32_32x32x16_bf16(vf10, bq0.v, oa1, 0, 0, 0); \
        oa1 = __builtin_amdgcn_mfma_f32_32x32x16_bf16(vf11, bq1.v, oa1, 0, 0, 0); \
    } while (0)

// Pack+partner-exchange p[16] -> two PV B-frags (BQA, BQB).
#define PACKP(p, BQA, BQB)                                                    \
    do {                                                                      \
        const unsigned P0 = pk2(p[0], p[1]),   P1 = pk2(p[2], p[3]);          \
        const unsigned P2 = pk2(p[4], p[5]),   P3 = pk2(p[6], p[7]);          \
        const unsigned P4 = pk2(p[8], p[9]),   P5 = pk2(p[10], p[11]);        \
        const unsigned P6 = pk2(p[12], p[13]), P7 = pk2(p[14], p[15]);        \
        const unsigned R0 = __shfl_xor(hi ? P0 : P2, 32, 64);                 \
        const unsigned R1 = __shfl_xor(hi ? P1 : P3, 32, 64);                 \
        const unsigned R2 = __shfl_xor(hi ? P4 : P6, 32, 64);                 \
        const unsigned R3 = __shfl_xor(hi ? P5 : P7, 32, 64);                 \
        BQA.w[0] = hi ? R0 : P0;  BQA.w[1] = hi ? R1 : P1;                    \
        BQA.w[2] = hi ? P2 : R0;  BQA.w[3] = hi ? P3 : R1;                    \
        BQB.w[0] = hi ? R2 : P4;  BQB.w[1] = hi ? R3 : P5;                    \
        BQB.w[2] = hi ? P6 : R2;  BQB.w[3] = hi ? P7 : R3;                    \
    } while (0)

// Joint KVBLK=64: subtiles KT (kA) and KT+1 (kB); ONE softmax update.
#define ATTN_TILE2(KT)                                                        \
    do {                                                                      \
        const int jb = (KT) * 32;                                             \
        const unsigned short* vb_ = Vtg + (size_t)l5 * 1024 + jb + hi8;       \
        const bf16x8 vf00 = *(const bf16x8*)(vb_);                            \
        const bf16x8 vf01 = *(const bf16x8*)(vb_ + 16);                       \
        const bf16x8 vf02 = *(const bf16x8*)(vb_ + 32);                       \
        const bf16x8 vf03 = *(const bf16x8*)(vb_ + 48);                       \
        const bf16x8 vf10 = *(const bf16x8*)(vb_ + 32768);                    \
        const bf16x8 vf11 = *(const bf16x8*)(vb_ + 32768 + 16);               \
        const bf16x8 vf12 = *(const bf16x8*)(vb_ + 32768 + 32);               \
        const bf16x8 vf13 = *(const bf16x8*)(vb_ + 32768 + 48);               \
        f32x16 s0v = {0.f}, s1v = {0.f};                                      \
        _Pragma("unroll")                                                     \
        for (int t = 0; t < 4; ++t) {                                         \
            s0v = __builtin_amdgcn_mfma_f32_32x32x16_bf16(kA[t], qf[t], s0v, 0, 0, 0); \
            s1v = __builtin_amdgcn_mfma_f32_32x32x16_bf16(kB[t], qf[t], s1v, 0, 0, 0); \
        }                                                                     \
        if ((KT) + 2 < nt) LOADK(kA, (KT) + 2);                               \
        if ((KT) + 3 < nt) LOADK(kB, (KT) + 3);                               \
        float p0[16], p1[16];                                                 \
        _Pragma("unroll")                                                     \
        for (int reg = 0; reg < 16; ++reg) {                                  \
            const int jo = (reg & 3) + 8 * (reg >> 2) + 4 * hi;               \
            p0[reg] = fmaf(s0v[reg], 0.125f, tb[q - jb - jo + 127]);          \
            p1[reg] = fmaf(s1v[reg], 0.125f, tb[q - jb - 32 - jo + 127]);     \
        }                                                                     \
        if (jb + 63 > qbase) {                                                \
            _Pragma("unroll")                                                 \
            for (int reg = 0; reg < 16; ++reg) {                              \
                const int jo = (reg & 3) + 8 * (reg >> 2) + 4 * hi;           \
                p0[reg] = (jb + jo <= q) ? p0[reg] : -1e30f;                  \
                p1[reg] = (jb + 32 + jo <= q) ? p1[reg] : -1e30f;             \
            }                                                                 \
        }                                                                     \
        float mx = p0[0];                                                     \
        _Pragma("unroll")                                                     \
        for (int reg = 1; reg < 16; ++reg) mx = fmaxf(mx, p0[reg]);           \
        _Pragma("unroll")                                                     \
        for (int reg = 0; reg < 16; ++reg) mx = fmaxf(mx, p1[reg]);           \
        mx = fmaxf(mx, __shfl_xor(mx, 32, 64));                               \
        if (!__all(mx <= mi + 8.f)) {                                         \
            const float mnew = fmaxf(mi, mx);                                 \
            const float alpha = __expf(mi - mnew);                            \
            mi = mnew;                                                        \
            li *= alpha;                                                      \
            _Pragma("unroll")                                                 \
            for (int reg = 0; reg < 16; ++reg) {                              \
                oa0[reg] *= alpha;                                            \
                oa1[reg] *= alpha;                                            \
            }                                                                 \
        }                                                                     \
        float lsum = 0.f;                                                     \
        _Pragma("unroll")                                                     \
        for (int reg = 0; reg < 16; ++reg) {                                  \
            p0[reg] = __expf(p0[reg] - mi);                                   \
            p1[reg] = __expf(p1[reg] - mi);                                   \
            lsum += p0[reg] + p1[reg];                                        \
        }                                                                     \
        li += lsum;                                                           \
        union { unsigned w[4]; bf16x8 v; } bq00, bq01, bq10, bq11;            \
        PACKP(p0, bq00, bq01);                                                \
        PACKP(p1, bq10, bq11);                                                \
        oa0 = __builtin_amdgcn_mfma_f32_32x32x16_bf16(vf00, bq00.v, oa0, 0, 0, 0); \
        oa1 = __builtin_amdgcn_mfma_f32_32x32x16_bf16(vf10, bq00.v, oa1, 0, 0, 0); \
        oa0 = __builtin_amdgcn_mfma_f32_32x32x16_bf16(vf01, bq01.v, oa0, 0, 0, 0); \
        oa1 = __builtin_amdgcn_mfma_f32_32x32x16_bf16(vf11, bq01.v, oa1, 0, 0, 0); \
        oa0 = __builtin_amdgcn_mfma_f32_32x32x16_bf16(vf02, bq10.v, oa0, 0, 0, 0); \
        oa1 = __builtin_amdgcn_mfma_f32_32x32x16_bf16(vf12, bq10.v, oa1, 0, 0, 0); \
        oa0 = __builtin_amdgcn_mfma_f32_32x32x16_bf16(vf03, bq11.v, oa0, 0, 0, 0); \
        oa1 = __builtin_amdgcn_mfma_f32_32x32x16_bf16(vf13, bq11.v, oa1, 0, 0, 0); \
    } while (0)

__global__ __launch_bounds__(128) void attn_mfma(const unsigned short* __restrict__ qkvb,
                                                 const float* __restrict__ table,
                                                 unsigned short* __restrict__ y) {
    const int bh = blockIdx.x, b = bh >> 4, h = bh & 15;
    const int level = 15 - blockIdx.y;      // 15..0, longest blocks first
    const int tid = threadIdx.x, lane = tid & 63, wave = tid >> 6;  // wave 0..1
    const int l5 = lane & 31, hi = lane >> 5, hi8 = hi * 8;

    __shared__ float tb[1152];

    const unsigned short* Qg  = qkvb + ((size_t)(b)*16 + h) * 65536;       // [t][d]
    const unsigned short* Kg  = qkvb + ((size_t)(4 + b)*16 + h) * 65536;   // [t][d]
    const unsigned short* Vtg = qkvb + ((size_t)(8 + b)*16 + h) * 65536;   // [d][t]

    const int qbase = 64 * level + 32 * wave;
    const int q = qbase + l5;               // ONE query per lane
    const int nt = 2 * level + wave + 1;    // exact causal 32-j tile count

    // Q fragment (MFMA B-operand): B[col=q][k = t*16 + hi*8 + e]
    bf16x8 qf[4];
    {
        const unsigned short* qr = Qg + (size_t)q * 64 + hi8;
#pragma unroll
        for (int t = 0; t < 4; ++t) qf[t] = *(const bf16x8*)(qr + t * 16);
    }

    // tb[i] = table[(896+i)*16+h]; needed i = q-j+127 in [96, 64*level+190]
    const int tbn = 64 * level + 191;
    for (int i = tid; i < tbn; i += 128) tb[i] = table[(896 + i) * 16 + h];
    __syncthreads();  // tb ready; only block-wide sync in the kernel

    f32x16 oa0 = {0.f}, oa1 = {0.f};  // O^T d-halves: row d, col q (own lane)
    float mi = -1e30f, li = 0.f;

    bf16x8 kA[4], kB[4];
    LOADK(kA, 0);
    LOADK(kB, nt > 1 ? 1 : 0);
    int kt = 0;
    for (; kt + 1 < nt; kt += 2) ATTN_TILE2(kt);
    if (kt < nt) ATTN_TILE(kA, kt);  // odd-nt tail (kA prefetched by pair loop)

    // epilogue: li = own + partner halves (1 shfl); O^T/li -> y.
    li += __shfl_xor(li, 32, 64);
    const float linv = 1.0f / li;
    // lane's d = dh*32 + 8*g + 4*hi + (0..3)  (reg = 4g..4g+3 consecutive)
    unsigned short* yq = y + ((size_t)(b * 1024 + q)) * 1024 + h * 64;
#pragma unroll
    for (int g = 0; g < 4; ++g) {
        union { unsigned short u[4]; int2 v; } o4a, o4b;
#pragma unroll
        for (int i = 0; i < 4; ++i) {
            o4a.u[i] = f2bf(oa0[4 * g + i] * linv);
            o4b.u[i] = f2bf(oa1[4 * g + i] * linv);
        }
        *(int2*)(yq + 8 * g + 4 * hi) = o4a.v;
        *(int2*)(yq + 32 + 8 * g + 4 * hi) = o4b.v;
    }
}

extern "C" void kernel_launch(void* const* d_in, const int* in_sizes, int n_in,
                              void* d_out, int out_size, void* d_ws, size_t ws_size,
                              hipStream_t stream) {
    const float* x      = (const float*)d_in[0];
    const float* qkv_w  = (const float*)d_in[1];
    const float* qkv_b  = (const float*)d_in[2];
    const float* proj_w = (const float*)d_in[3];
    const float* proj_b = (const float*)d_in[4];
    const float* rel    = (const float*)d_in[5];
    float* out = (float*)d_out;

    char* ws = (char*)d_ws;
    unsigned short* xb   = (unsigned short*)(ws + 0);
    unsigned short* qwb  = (unsigned short*)(ws + 8388608);
    unsigned short* pwb  = (unsigned short*)(ws + 14680064);
    float* table         = (float*)(ws + 16777216);
    unsigned short* qkvb = (unsigned short*)(ws + 16908288);
    unsigned short* yb   = (unsigned short*)(ws + 42074112);

    cvt3<<<4096, 256, 0, stream>>>(x, qkv_w, proj_w, xb, qwb, pwb);
    table_reduce<<<2047, 1024, 0, stream>>>(rel, table);
    gemm_bt<0><<<dim3(32, 24), 512, 0, stream>>>(xb, qwb, qkv_b, qkvb, nullptr,
                                                 4096, 3072, 1024);
    attn_mfma<<<dim3(64, 16), 128, 0, stream>>>(qkvb, table, yb);
    gemm_bt<1><<<dim3(32, 8), 512, 0, stream>>>(yb, pwb, proj_b, nullptr, out,
                                                4096, 1024, 1024);
}

// Round 16
// 193.239 us; speedup vs baseline: 1.1174x; 1.0074x over previous
//
#include <hip/hip_runtime.h>
#include <hip/hip_bf16.h>
#include <cstdint>

// Problem: B=4, T=1024, C=1024, H=16, D=64, MAX_LEN=1024, NPOS=2047
// Pipeline (R37):
//   cvt3: x, qkv_w, proj_w fp32 -> bf16 in ws (measured ~96% HBM peak: done)
//   table_reduce rel_pos_emb -> (2047,16)  [1-wave-per-head]
//   gemm_bt<0>: qkv = xb @ qwb^T + b -> scatter bf16; Q,K (B,H,T,D), V (B,H,D,T)
//   attn_mfma: flash causal, 32x32 lane-local softmax, KVBLK=64 + defer-max
//   gemm_bt<1>: out = y @ pwb^T + b -> fp32 d_out
//
// R35 post-mortem: LB(512,5) did NOT move the VGPR-32 lottery (falsifier hit:
// still 32/44.3us). attn revert OK (total 194.7 ~ best).
// R37 changes:
//  1. gemm_bt: true double-buffer (T3-minimum). Old: stage;sync;compute;sync
//     (latency fully exposed at each drain). New: stage NEXT tile -> compute
//     CURRENT -> sync, 2x-unrolled for compile-time buffer indices. LDS
//     16->32KB (still wave-limited 4 blocks/CU -- no occupancy cost; m132's
//     failure was 64KB). Barriers halve (1/K-step) AND loads overlap MFMA.
//     m99/m100 measured dbuf null on the healthy 874 baseline; ours is a
//     pathological 580/VGPR-32 schedule + this re-rolls the rule-19 lottery.
//  2. attn PACKP: shfl_xor+cndmask exchange -> v_permlane32_swap_b32 (T12
//     primitive, m255 1.20x; exact lane l<->l+32 semantics match). Deletes
//     8 bpermutes + 16 cndmasks per TILE2 from the serial spine.
//
// Workspace layout (bytes):
//   xb   @ 0         : 4096x1024 bf16  (8 MB)
//   qwb  @ 8388608   : 3072x1024 bf16  (6 MB)
//   pwb  @ 14680064  : 1024x1024 bf16  (2 MB)
//   table@ 16777216  : 2047x16 f32     (128 KB)
//   qkvb @ 16908288  : (3,4,16,64K) bf16 (24 MB)
//   y    @ 42074112  : 4096x1024 bf16  (8 MB)

typedef __bf16 bf16x8 __attribute__((ext_vector_type(8)));
typedef float f32x4 __attribute__((ext_vector_type(4)));
typedef float f32x16 __attribute__((ext_vector_type(16)));

__device__ __forceinline__ float bf2f(unsigned short u) {
    return __uint_as_float(((unsigned)u) << 16);
}
__device__ __forceinline__ unsigned short f2bf(float f) {
    __hip_bfloat16 h = __float2bfloat16(f);
    return *reinterpret_cast<unsigned short*>(&h);
}
__device__ __forceinline__ unsigned pk2(float a, float b) {
    return (unsigned)f2bf(a) | ((unsigned)f2bf(b) << 16);
}
__device__ __forceinline__ int4 cvt8(float4 a, float4 b) {
    union { unsigned short s[8]; int4 v; } u;
    u.s[0] = f2bf(a.x); u.s[1] = f2bf(a.y); u.s[2] = f2bf(a.z); u.s[3] = f2bf(a.w);
    u.s[4] = f2bf(b.x); u.s[5] = f2bf(b.y); u.s[6] = f2bf(b.z); u.s[7] = f2bf(b.w);
    return u.v;
}

// async global->LDS, 16B per lane. LDS dest must be linear base+lane*16.
__device__ __forceinline__ void gload16(const void* g, void* l) {
    __builtin_amdgcn_global_load_lds(
        reinterpret_cast<const __attribute__((address_space(1))) unsigned int*>(
            reinterpret_cast<uintptr_t>(g)),
        reinterpret_cast<__attribute__((address_space(3))) unsigned int*>(
            reinterpret_cast<uintptr_t>(l)),
        16, 0, 0);
}

// ---------------- fp32 -> bf16 one-shot convert (x, qkv_w, proj_w) ----------
__global__ __launch_bounds__(256) void cvt3(const float* __restrict__ x,
                                            const float* __restrict__ w1,
                                            const float* __restrict__ w2,
                                            unsigned short* __restrict__ ox,
                                            unsigned short* __restrict__ ow1,
                                            unsigned short* __restrict__ ow2) {
    const int i = blockIdx.x * 256 + threadIdx.x;
    const float* s; unsigned short* d; int li;
    if (i < 524288)      { s = x;  d = ox;  li = i; }
    else if (i < 917504) { s = w1; d = ow1; li = i - 524288; }
    else                 { s = w2; d = ow2; li = i - 917504; }
    const float4 a = *(const float4*)(s + (size_t)li * 8);
    const float4 b = *(const float4*)(s + (size_t)li * 8 + 4);
    *(int4*)(d + (size_t)li * 8) = cvt8(a, b);
}

// ---------------- rel_pos_emb (2047,1024) -> table (2047,16) ----------------
// 1024 thr = 16 waves; wave w sums head w's 64 d's: coalesced load + single
// 6-shfl tree.
__global__ __launch_bounds__(1024) void table_reduce(const float* __restrict__ rel,
                                                     float* __restrict__ table) {
    const int p = blockIdx.x;
    const int w = threadIdx.x >> 6, lane = threadIdx.x & 63;
    float v = rel[(size_t)p * 1024 + w * 64 + lane];
#pragma unroll
    for (int o = 32; o; o >>= 1) v += __shfl_xor(v, o, 64);
    if (lane == 0) table[p * 16 + w] = v;
}

// ---------------- bf16 MFMA GEMM: C = A B^T + bias (dbuf T3-minimum) --------
// 512 threads, 8 waves: wr=wave&1 (64-row half), wc=wave>>1 (32-col quarter).
// Double-buffered LDS (2 x [128][32] per matrix = 32KB): stage tile t+1 via
// gload_lds 16B BEFORE computing tile t; ONE __syncthreads per K-step (its
// implicit vmcnt(0) drain waits the prefetch that flew during the MFMAs).
// 2x-unrolled so buffer indices are compile-time.
// EPI=0: scatter bf16 into qkv planes (Q,K [t][d], V [d][t]). EPI=1: fp32 out.
#define GSTEP(AS_, BS_)                                                       \
    do {                                                                      \
        bf16x8 af[4], bfr[2];                                                 \
        _Pragma("unroll")                                                     \
        for (int r = 0; r < 4; ++r)                                           \
            af[r] = *(const bf16x8*)(&AS_[(64 * wr + 16 * r + lm) * 32 + quad * 8]); \
        _Pragma("unroll")                                                     \
        for (int c = 0; c < 2; ++c)                                           \
            bfr[c] = *(const bf16x8*)(&BS_[(32 * wc + 16 * c + lm) * 32 + quad * 8]); \
        _Pragma("unroll")                                                     \
        for (int r = 0; r < 4; ++r)                                           \
            _Pragma("unroll")                                                 \
            for (int c = 0; c < 2; ++c)                                       \
                acc[r][c] = __builtin_amdgcn_mfma_f32_16x16x32_bf16(af[r], bfr[c], acc[r][c], 0, 0, 0); \
    } while (0)

template <int EPI>
__global__ __launch_bounds__(512) void gemm_bt(const unsigned short* __restrict__ A,
                                               const unsigned short* __restrict__ B,
                                               const float* __restrict__ bias,
                                               unsigned short* __restrict__ outb,
                                               float* __restrict__ outf,
                                               int M, int N, int K) {
    __shared__ __attribute__((aligned(16))) unsigned short As0[128 * 32];
    __shared__ __attribute__((aligned(16))) unsigned short Bs0[128 * 32];
    __shared__ __attribute__((aligned(16))) unsigned short As1[128 * 32];
    __shared__ __attribute__((aligned(16))) unsigned short Bs1[128 * 32];
    const int bm = blockIdx.x * 128, bn = blockIdx.y * 128;
    const int tid = threadIdx.x, lane = tid & 63, wave = tid >> 6;
    const int wr = wave & 1, wc = wave >> 1;  // wc in 0..3
    const int quad = lane >> 4, lm = lane & 15;

    const int srow = tid >> 2;        // 0..127
    const int scol = (tid & 3) * 8;   // shorts
    const unsigned short* Ap = A + (size_t)(bm + srow) * K + scol;
    const unsigned short* Bp = B + (size_t)(bn + srow) * K + scol;
    unsigned short* AsW0 = &As0[tid * 8];   // row srow, col scol (linear)
    unsigned short* BsW0 = &Bs0[tid * 8];
    unsigned short* AsW1 = &As1[tid * 8];
    unsigned short* BsW1 = &Bs1[tid * 8];

    f32x4 acc[4][2];
#pragma unroll
    for (int r = 0; r < 4; ++r)
#pragma unroll
        for (int c = 0; c < 2; ++c) acc[r][c] = (f32x4){0.f, 0.f, 0.f, 0.f};

    // prologue: tile 0 -> buf0
    gload16(Ap, AsW0);
    gload16(Bp, BsW0);
    __syncthreads();  // drain (implicit vmcnt(0)) + all waves ready

    for (int kk = 0; kk < K; kk += 64) {
        // half A: stage kk+32 -> buf1 (flies during compute), compute buf0
        if (kk + 32 < K) {
            gload16(Ap + kk + 32, AsW1);
            gload16(Bp + kk + 32, BsW1);
        }
        GSTEP(As0, Bs0);
        __syncthreads();  // waits buf1 loads + protects buf0 for next stage

        // half B: stage kk+64 -> buf0, compute buf1
        if (kk + 64 < K) {
            gload16(Ap + kk + 64, AsW0);
            gload16(Bp + kk + 64, BsW0);
        }
        GSTEP(As1, Bs1);
        __syncthreads();
    }

    // C/D layout: col = lane&15, row = (lane>>4)*4 + reg
#pragma unroll
    for (int r = 0; r < 4; ++r)
#pragma unroll
        for (int c = 0; c < 2; ++c)
#pragma unroll
            for (int i = 0; i < 4; ++i) {
                const int row = bm + 64 * wr + 16 * r + quad * 4 + i;
                const int col = bn + 32 * wc + 16 * c + lm;
                const float v = acc[r][c][i] + bias[col];
                if (EPI == 0) {
                    const int b = row >> 10, t = row & 1023;
                    const int s3 = col >> 10, rem = col & 1023;
                    const int h = rem >> 6, d = rem & 63;
                    const size_t base = (((size_t)s3 * 4 + b) * 16 + h) * 65536;
                    const size_t off = base + (s3 == 2 ? (size_t)d * 1024 + t
                                                       : (size_t)t * 64 + d);
                    outb[off] = f2bf(v);
                } else {
                    outf[(size_t)row * N + col] = v;
                }
            }
}

// ---------------- MFMA flash causal attention ------------------------------
// 32x32 lane-local softmax, KVBLK=64 joint tiles + T13 defer-max.
// R37: P-exchange via v_permlane32_swap_b32 (hi half of dst <-> lo half of
// src): after swap(Q0,Q2): Q0' = {Q0.lo, Q2.lo-from-partner}, Q2' =
// {Q0.hi-from-partner, Q2.hi} -- exactly the old shfl_xor+cndmask result.
#define LOADK(DST, KT)                                                        \
    do {                                                                      \
        const unsigned short* kr_ = Kg + (size_t)((KT) * 32 + l5) * 64 + hi8; \
        DST[0] = *(const bf16x8*)(kr_);                                       \
        DST[1] = *(const bf16x8*)(kr_ + 16);                                  \
        DST[2] = *(const bf16x8*)(kr_ + 32);                                  \
        DST[3] = *(const bf16x8*)(kr_ + 48);                                  \
    } while (0)

// Pack + partner-exchange p[16] -> two PV B-frags (BQA, BQB), in-register.
#define PACKP(p, BQA, BQB)                                                    \
    do {                                                                      \
        unsigned Q0 = pk2(p[0], p[1]),   Q1 = pk2(p[2], p[3]);                \
        unsigned Q2 = pk2(p[4], p[5]),   Q3 = pk2(p[6], p[7]);                \
        unsigned Q4 = pk2(p[8], p[9]),   Q5 = pk2(p[10], p[11]);              \
        unsigned Q6 = pk2(p[12], p[13]), Q7 = pk2(p[14], p[15]);              \
        asm volatile("v_permlane32_swap_b32 %0, %1" : "+v"(Q0), "+v"(Q2));    \
        asm volatile("v_permlane32_swap_b32 %0, %1" : "+v"(Q1), "+v"(Q3));    \
        asm volatile("v_permlane32_swap_b32 %0, %1" : "+v"(Q4), "+v"(Q6));    \
        asm volatile("v_permlane32_swap_b32 %0, %1" : "+v"(Q5), "+v"(Q7));    \
        BQA.w[0] = Q0;  BQA.w[1] = Q1;  BQA.w[2] = Q2;  BQA.w[3] = Q3;        \
        BQB.w[0] = Q4;  BQB.w[1] = Q5;  BQB.w[2] = Q6;  BQB.w[3] = Q7;        \
    } while (0)

// Single 32-j tile (tail only; always-rescale path). Uses kA-style frag KF.
#define ATTN_TILE(KF, KT)                                                     \
    do {                                                                      \
        const int jb = (KT) * 32;                                             \
        const unsigned short* vb_ = Vtg + (size_t)l5 * 1024 + jb + hi8;       \
        const bf16x8 vf00 = *(const bf16x8*)(vb_);                            \
        const bf16x8 vf01 = *(const bf16x8*)(vb_ + 16);                       \
        const bf16x8 vf10 = *(const bf16x8*)(vb_ + 32768);                    \
        const bf16x8 vf11 = *(const bf16x8*)(vb_ + 32768 + 16);               \
        f32x16 s = {0.f};                                                     \
        _Pragma("unroll")                                                     \
        for (int t = 0; t < 4; ++t)                                           \
            s = __builtin_amdgcn_mfma_f32_32x32x16_bf16(KF[t], qf[t], s, 0, 0, 0); \
        float p[16];                                                          \
        _Pragma("unroll")                                                     \
        for (int reg = 0; reg < 16; ++reg) {                                  \
            const int j = jb + (reg & 3) + 8 * (reg >> 2) + 4 * hi;           \
            p[reg] = fmaf(s[reg], 0.125f, tb[q - j + 127]);                   \
        }                                                                     \
        if (jb + 31 > qbase) {                                                \
            _Pragma("unroll")                                                 \
            for (int reg = 0; reg < 16; ++reg) {                              \
                const int j = jb + (reg & 3) + 8 * (reg >> 2) + 4 * hi;       \
                p[reg] = (j <= q) ? p[reg] : -1e30f;                          \
            }                                                                 \
        }                                                                     \
        float mx = p[0];                                                      \
        _Pragma("unroll")                                                     \
        for (int reg = 1; reg < 16; ++reg) mx = fmaxf(mx, p[reg]);            \
        mx = fmaxf(mx, __shfl_xor(mx, 32, 64));                               \
        if (!__all(mx <= mi + 8.f)) {                                         \
            const float mnew = fmaxf(mi, mx);                                 \
            const float alpha = __expf(mi - mnew);                            \
            mi = mnew;                                                        \
            li *= alpha;                                                      \
            _Pragma("unroll")                                                 \
            for (int reg = 0; reg < 16; ++reg) {                              \
                oa0[reg] *= alpha;                                            \
                oa1[reg] *= alpha;                                            \
            }                                                                 \
        }                                                                     \
        float lsum = 0.f;                                                     \
        _Pragma("unroll")                                                     \
        for (int reg = 0; reg < 16; ++reg) {                                  \
            p[reg] = __expf(p[reg] - mi);                                     \
            lsum += p[reg];                                                   \
        }                                                                     \
        li += lsum;                                                           \
        union { unsigned w[4]; bf16x8 v; } bq0, bq1;                          \
        PACKP(p, bq0, bq1);                                                   \
        oa0 = __builtin_amdgcn_mfma_f32_32x32x16_bf16(vf00, bq0.v, oa0, 0, 0, 0); \
        oa0 = __builtin_amdgcn_mfma_f32_32x32x16_bf16(vf01, bq1.v, oa0, 0, 0, 0); \
        oa1 = __builtin_amdgcn_mfma_f32_32x32x16_bf16(vf10, bq0.v, oa1, 0, 0, 0); \
        oa1 = __builtin_amdgcn_mfma_f32_32x32x16_bf16(vf11, bq1.v, oa1, 0, 0, 0); \
    } while (0)

// Joint KVBLK=64: subtiles KT (kA) and KT+1 (kB); ONE softmax update.
#define ATTN_TILE2(KT)                                                        \
    do {                                                                      \
        const int jb = (KT) * 32;                                             \
        const unsigned short* vb_ = Vtg + (size_t)l5 * 1024 + jb + hi8;       \
        const bf16x8 vf00 = *(const bf16x8*)(vb_);                            \
        const bf16x8 vf01 = *(const bf16x8*)(vb_ + 16);                       \
        const bf16x8 vf02 = *(const bf16x8*)(vb_ + 32);                       \
        const bf16x8 vf03 = *(const bf16x8*)(vb_ + 48);                       \
        const bf16x8 vf10 = *(const bf16x8*)(vb_ + 32768);                    \
        const bf16x8 vf11 = *(const bf16x8*)(vb_ + 32768 + 16);               \
        const bf16x8 vf12 = *(const bf16x8*)(vb_ + 32768 + 32);               \
        const bf16x8 vf13 = *(const bf16x8*)(vb_ + 32768 + 48);               \
        f32x16 s0v = {0.f}, s1v = {0.f};                                      \
        _Pragma("unroll")                                                     \
        for (int t = 0; t < 4; ++t) {                                         \
            s0v = __builtin_amdgcn_mfma_f32_32x32x16_bf16(kA[t], qf[t], s0v, 0, 0, 0); \
            s1v = __builtin_amdgcn_mfma_f32_32x32x16_bf16(kB[t], qf[t], s1v, 0, 0, 0); \
        }                                                                     \
        if ((KT) + 2 < nt) LOADK(kA, (KT) + 2);                               \
        if ((KT) + 3 < nt) LOADK(kB, (KT) + 3);                               \
        float p0[16], p1[16];                                                 \
        _Pragma("unroll")                                                     \
        for (int reg = 0; reg < 16; ++reg) {                                  \
            const int jo = (reg & 3) + 8 * (reg >> 2) + 4 * hi;               \
            p0[reg] = fmaf(s0v[reg], 0.125f, tb[q - jb - jo + 127]);          \
            p1[reg] = fmaf(s1v[reg], 0.125f, tb[q - jb - 32 - jo + 127]);     \
        }                                                                     \
        if (jb + 63 > qbase) {                                                \
            _Pragma("unroll")                                                 \
            for (int reg = 0; reg < 16; ++reg) {                              \
                const int jo = (reg & 3) + 8 * (reg >> 2) + 4 * hi;           \
                p0[reg] = (jb + jo <= q) ? p0[reg] : -1e30f;                  \
                p1[reg] = (jb + 32 + jo <= q) ? p1[reg] : -1e30f;             \
            }                                                                 \
        }                                                                     \
        float mx = p0[0];                                                     \
        _Pragma("unroll")                                                     \
        for (int reg = 1; reg < 16; ++reg) mx = fmaxf(mx, p0[reg]);           \
        _Pragma("unroll")                                                     \
        for (int reg = 0; reg < 16; ++reg) mx = fmaxf(mx, p1[reg]);           \
        mx = fmaxf(mx, __shfl_xor(mx, 32, 64));                               \
        if (!__all(mx <= mi + 8.f)) {                                         \
            const float mnew = fmaxf(mi, mx);                                 \
            const float alpha = __expf(mi - mnew);                            \
            mi = mnew;                                                        \
            li *= alpha;                                                      \
            _Pragma("unroll")                                                 \
            for (int reg = 0; reg < 16; ++reg) {                              \
                oa0[reg] *= alpha;                                            \
                oa1[reg] *= alpha;                                            \
            }                                                                 \
        }                                                                     \
        float lsum = 0.f;                                                     \
        _Pragma("unroll")                                                     \
        for (int reg = 0; reg < 16; ++reg) {                                  \
            p0[reg] = __expf(p0[reg] - mi);                                   \
            p1[reg] = __expf(p1[reg] - mi);                                   \
            lsum += p0[reg] + p1[reg];                                        \
        }                                                                     \
        li += lsum;                                                           \
        union { unsigned w[4]; bf16x8 v; } bq00, bq01, bq10, bq11;            \
        PACKP(p0, bq00, bq01);                                                \
        PACKP(p1, bq10, bq11);                                                \
        oa0 = __builtin_amdgcn_mfma_f32_32x32x16_bf16(vf00, bq00.v, oa0, 0, 0, 0); \
        oa1 = __builtin_amdgcn_mfma_f32_32x32x16_bf16(vf10, bq00.v, oa1, 0, 0, 0); \
        oa0 = __builtin_amdgcn_mfma_f32_32x32x16_bf16(vf01, bq01.v, oa0, 0, 0, 0); \
        oa1 = __builtin_amdgcn_mfma_f32_32x32x16_bf16(vf11, bq01.v, oa1, 0, 0, 0); \
        oa0 = __builtin_amdgcn_mfma_f32_32x32x16_bf16(vf02, bq10.v, oa0, 0, 0, 0); \
        oa1 = __builtin_amdgcn_mfma_f32_32x32x16_bf16(vf12, bq10.v, oa1, 0, 0, 0); \
        oa0 = __builtin_amdgcn_mfma_f32_32x32x16_bf16(vf03, bq11.v, oa0, 0, 0, 0); \
        oa1 = __builtin_amdgcn_mfma_f32_32x32x16_bf16(vf13, bq11.v, oa1, 0, 0, 0); \
    } while (0)

__global__ __launch_bounds__(128) void attn_mfma(const unsigned short* __restrict__ qkvb,
                                                 const float* __restrict__ table,
                                                 unsigned short* __restrict__ y) {
    const int bh = blockIdx.x, b = bh >> 4, h = bh & 15;
    const int level = 15 - blockIdx.y;      // 15..0, longest blocks first
    const int tid = threadIdx.x, lane = tid & 63, wave = tid >> 6;  // wave 0..1
    const int l5 = lane & 31, hi = lane >> 5, hi8 = hi * 8;

    __shared__ float tb[1152];

    const unsigned short* Qg  = qkvb + ((size_t)(b)*16 + h) * 65536;       // [t][d]
    const unsigned short* Kg  = qkvb + ((size_t)(4 + b)*16 + h) * 65536;   // [t][d]
    const unsigned short* Vtg = qkvb + ((size_t)(8 + b)*16 + h) * 65536;   // [d][t]

    const int qbase = 64 * level + 32 * wave;
    const int q = qbase + l5;               // ONE query per lane
    const int nt = 2 * level + wave + 1;    // exact causal 32-j tile count

    // Q fragment (MFMA B-operand): B[col=q][k = t*16 + hi*8 + e]
    bf16x8 qf[4];
    {
        const unsigned short* qr = Qg + (size_t)q * 64 + hi8;
#pragma unroll
        for (int t = 0; t < 4; ++t) qf[t] = *(const bf16x8*)(qr + t * 16);
    }

    // tb[i] = table[(896+i)*16+h]; needed i = q-j+127 in [96, 64*level+190]
    const int tbn = 64 * level + 191;
    for (int i = tid; i < tbn; i += 128) tb[i] = table[(896 + i) * 16 + h];
    __syncthreads();  // tb ready; only block-wide sync in the kernel

    f32x16 oa0 = {0.f}, oa1 = {0.f};  // O^T d-halves: row d, col q (own lane)
    float mi = -1e30f, li = 0.f;

    bf16x8 kA[4], kB[4];
    LOADK(kA, 0);
    LOADK(kB, nt > 1 ? 1 : 0);
    int kt = 0;
    for (; kt + 1 < nt; kt += 2) ATTN_TILE2(kt);
    if (kt < nt) ATTN_TILE(kA, kt);  // odd-nt tail (kA prefetched by pair loop)

    // epilogue: li = own + partner halves (1 shfl); O^T/li -> y.
    li += __shfl_xor(li, 32, 64);
    const float linv = 1.0f / li;
    // lane's d = dh*32 + 8*g + 4*hi + (0..3)  (reg = 4g..4g+3 consecutive)
    unsigned short* yq = y + ((size_t)(b * 1024 + q)) * 1024 + h * 64;
#pragma unroll
    for (int g = 0; g < 4; ++g) {
        union { unsigned short u[4]; int2 v; } o4a, o4b;
#pragma unroll
        for (int i = 0; i < 4; ++i) {
            o4a.u[i] = f2bf(oa0[4 * g + i] * linv);
            o4b.u[i] = f2bf(oa1[4 * g + i] * linv);
        }
        *(int2*)(yq + 8 * g + 4 * hi) = o4a.v;
        *(int2*)(yq + 32 + 8 * g + 4 * hi) = o4b.v;
    }
}

extern "C" void kernel_launch(void* const* d_in, const int* in_sizes, int n_in,
                              void* d_out, int out_size, void* d_ws, size_t ws_size,
                              hipStream_t stream) {
    const float* x      = (const float*)d_in[0];
    const float* qkv_w  = (const float*)d_in[1];
    const float* qkv_b  = (const float*)d_in[2];
    const float* proj_w = (const float*)d_in[3];
    const float* proj_b = (const float*)d_in[4];
    const float* rel    = (const float*)d_in[5];
    float* out = (float*)d_out;

    char* ws = (char*)d_ws;
    unsigned short* xb   = (unsigned short*)(ws + 0);
    unsigned short* qwb  = (unsigned short*)(ws + 8388608);
    unsigned short* pwb  = (unsigned short*)(ws + 14680064);
    float* table         = (float*)(ws + 16777216);
    unsigned short* qkvb = (unsigned short*)(ws + 16908288);
    unsigned short* yb   = (unsigned short*)(ws + 42074112);

    cvt3<<<4096, 256, 0, stream>>>(x, qkv_w, proj_w, xb, qwb, pwb);
    table_reduce<<<2047, 1024, 0, stream>>>(rel, table);
    gemm_bt<0><<<dim3(32, 24), 512, 0, stream>>>(xb, qwb, qkv_b, qkvb, nullptr,
                                                 4096, 3072, 1024);
    attn_mfma<<<dim3(64, 16), 128, 0, stream>>>(qkvb, table, yb);
    gemm_bt<1><<<dim3(32, 8), 512, 0, stream>>>(yb, pwb, proj_b, nullptr, out,
                                                4096, 1024, 1024);
}

// Round 17
// 181.913 us; speedup vs baseline: 1.1869x; 1.0623x over previous
//
#include <hip/hip_runtime.h>
#include <hip/hip_bf16.h>
#include <cstdint>

// Problem: B=4, T=1024, C=1024, H=16, D=64, MAX_LEN=1024, NPOS=2047
// Pipeline (R39):
//   cvt3: x, qkv_w, proj_w fp32 -> bf16 in ws (measured ~96% HBM peak: done)
//   table_reduce rel_pos_emb -> (2047,16)  [1-wave-per-head]
//   gemm_bt<0>: qkv = xb @ qwb^T + b -> scatter bf16; Q,K (B,H,T,D), V (B,H,D,T)
//   attn_mfma: flash causal, 32x32 lane-local softmax, KVBLK=64 + defer-max
//   gemm_bt<1>: out = y @ pwb^T + b -> fp32 d_out
//
// R37 post-mortem: 2-deep dbuf FLAT (43.8us, MfmaUtil 23%) -- with 2 buffers
// the pre-compute wait has nothing else in flight -> full drain (T4 lesson,
// m218: the 8-phase gain IS counted vmcnt). attn permlane kept (~40us).
// ~86us of dur_us is harness workspace-fill (2x 256MB memset) -- untouchable.
// R39: 3-deep pipeline (48KB LDS, 3 blocks/CU = 24 waves -- above m132's
// 2-block failure regime). Step t: issue t+2 loads, compute t, then
// s_waitcnt vmcnt(2) (waits ONLY t+1's loads; t+2's 2 stay in flight) +
// RAW s_barrier (no compiler drain) + sched_barrier(0) (rule 18). 3x-grouped
// loop gives compile-time buffer names (rule 20); 2-step tail (nst=32).
// Falsifier: gemm0 flat ~44 / MfmaUtil ~23 -> compiler inserted its own
// vmcnt(0) (m131-style defeat) -> 2-phase lineage closed.
//
// Workspace layout (bytes):
//   xb   @ 0         : 4096x1024 bf16  (8 MB)
//   qwb  @ 8388608   : 3072x1024 bf16  (6 MB)
//   pwb  @ 14680064  : 1024x1024 bf16  (2 MB)
//   table@ 16777216  : 2047x16 f32     (128 KB)
//   qkvb @ 16908288  : (3,4,16,64K) bf16 (24 MB)
//   y    @ 42074112  : 4096x1024 bf16  (8 MB)

typedef __bf16 bf16x8 __attribute__((ext_vector_type(8)));
typedef float f32x4 __attribute__((ext_vector_type(4)));
typedef float f32x16 __attribute__((ext_vector_type(16)));

__device__ __forceinline__ float bf2f(unsigned short u) {
    return __uint_as_float(((unsigned)u) << 16);
}
__device__ __forceinline__ unsigned short f2bf(float f) {
    __hip_bfloat16 h = __float2bfloat16(f);
    return *reinterpret_cast<unsigned short*>(&h);
}
__device__ __forceinline__ unsigned pk2(float a, float b) {
    return (unsigned)f2bf(a) | ((unsigned)f2bf(b) << 16);
}
__device__ __forceinline__ int4 cvt8(float4 a, float4 b) {
    union { unsigned short s[8]; int4 v; } u;
    u.s[0] = f2bf(a.x); u.s[1] = f2bf(a.y); u.s[2] = f2bf(a.z); u.s[3] = f2bf(a.w);
    u.s[4] = f2bf(b.x); u.s[5] = f2bf(b.y); u.s[6] = f2bf(b.z); u.s[7] = f2bf(b.w);
    return u.v;
}

// async global->LDS, 16B per lane. LDS dest must be linear base+lane*16.
__device__ __forceinline__ void gload16(const void* g, void* l) {
    __builtin_amdgcn_global_load_lds(
        reinterpret_cast<const __attribute__((address_space(1))) unsigned int*>(
            reinterpret_cast<uintptr_t>(g)),
        reinterpret_cast<__attribute__((address_space(3))) unsigned int*>(
            reinterpret_cast<uintptr_t>(l)),
        16, 0, 0);
}

// ---------------- fp32 -> bf16 one-shot convert (x, qkv_w, proj_w) ----------
__global__ __launch_bounds__(256) void cvt3(const float* __restrict__ x,
                                            const float* __restrict__ w1,
                                            const float* __restrict__ w2,
                                            unsigned short* __restrict__ ox,
                                            unsigned short* __restrict__ ow1,
                                            unsigned short* __restrict__ ow2) {
    const int i = blockIdx.x * 256 + threadIdx.x;
    const float* s; unsigned short* d; int li;
    if (i < 524288)      { s = x;  d = ox;  li = i; }
    else if (i < 917504) { s = w1; d = ow1; li = i - 524288; }
    else                 { s = w2; d = ow2; li = i - 917504; }
    const float4 a = *(const float4*)(s + (size_t)li * 8);
    const float4 b = *(const float4*)(s + (size_t)li * 8 + 4);
    *(int4*)(d + (size_t)li * 8) = cvt8(a, b);
}

// ---------------- rel_pos_emb (2047,1024) -> table (2047,16) ----------------
// 1024 thr = 16 waves; wave w sums head w's 64 d's: coalesced load + single
// 6-shfl tree.
__global__ __launch_bounds__(1024) void table_reduce(const float* __restrict__ rel,
                                                     float* __restrict__ table) {
    const int p = blockIdx.x;
    const int w = threadIdx.x >> 6, lane = threadIdx.x & 63;
    float v = rel[(size_t)p * 1024 + w * 64 + lane];
#pragma unroll
    for (int o = 32; o; o >>= 1) v += __shfl_xor(v, o, 64);
    if (lane == 0) table[p * 16 + w] = v;
}

// ---------------- bf16 MFMA GEMM: C = A B^T + bias (3-deep counted vmcnt) ---
// 512 threads, 8 waves: wr=wave&1 (64-row half), wc=wave>>1 (32-col quarter).
// 3 LDS buffer pairs (48KB). Step t: issue t+2 -> buf[(t+2)%3], compute
// buf[t%3], s_waitcnt vmcnt(2) (t+1's loads retired, t+2's in flight),
// RAW s_barrier. Buffer (t+2)%3 == (t-1)%3 was last read at step t-1 --
// protected by that step's barrier. nst = K/32 = 32 for both calls.
#define GSTEP(AS_, BS_)                                                       \
    do {                                                                      \
        bf16x8 af[4], bfr[2];                                                 \
        _Pragma("unroll")                                                     \
        for (int r = 0; r < 4; ++r)                                           \
            af[r] = *(const bf16x8*)(&AS_[(64 * wr + 16 * r + lm) * 32 + quad * 8]); \
        _Pragma("unroll")                                                     \
        for (int c = 0; c < 2; ++c)                                           \
            bfr[c] = *(const bf16x8*)(&BS_[(32 * wc + 16 * c + lm) * 32 + quad * 8]); \
        _Pragma("unroll")                                                     \
        for (int r = 0; r < 4; ++r)                                           \
            _Pragma("unroll")                                                 \
            for (int c = 0; c < 2; ++c)                                       \
                acc[r][c] = __builtin_amdgcn_mfma_f32_16x16x32_bf16(af[r], bfr[c], acc[r][c], 0, 0, 0); \
    } while (0)

// one pipelined step: prefetch T+2 into (APF,BPF), compute (ACUR,BCUR),
// counted wait + raw barrier.
#define PSTEP(ACUR, BCUR, APF, BPF, T)                                        \
    do {                                                                      \
        if ((T) + 2 < nst) {                                                  \
            gload16(Ap + ((T) + 2) * 32, &APF[tid * 8]);                      \
            gload16(Bp + ((T) + 2) * 32, &BPF[tid * 8]);                      \
        }                                                                     \
        GSTEP(ACUR, BCUR);                                                    \
        asm volatile("s_waitcnt vmcnt(2)" ::: "memory");                      \
        __builtin_amdgcn_s_barrier();                                         \
        __builtin_amdgcn_sched_barrier(0);                                    \
    } while (0)

template <int EPI>
__global__ __launch_bounds__(512) void gemm_bt(const unsigned short* __restrict__ A,
                                               const unsigned short* __restrict__ B,
                                               const float* __restrict__ bias,
                                               unsigned short* __restrict__ outb,
                                               float* __restrict__ outf,
                                               int M, int N, int K) {
    __shared__ __attribute__((aligned(16))) unsigned short As0[128 * 32];
    __shared__ __attribute__((aligned(16))) unsigned short Bs0[128 * 32];
    __shared__ __attribute__((aligned(16))) unsigned short As1[128 * 32];
    __shared__ __attribute__((aligned(16))) unsigned short Bs1[128 * 32];
    __shared__ __attribute__((aligned(16))) unsigned short As2[128 * 32];
    __shared__ __attribute__((aligned(16))) unsigned short Bs2[128 * 32];
    const int bm = blockIdx.x * 128, bn = blockIdx.y * 128;
    const int tid = threadIdx.x, lane = tid & 63, wave = tid >> 6;
    const int wr = wave & 1, wc = wave >> 1;  // wc in 0..3
    const int quad = lane >> 4, lm = lane & 15;

    const int srow = tid >> 2;        // 0..127
    const int scol = (tid & 3) * 8;   // shorts
    const unsigned short* Ap = A + (size_t)(bm + srow) * K + scol;
    const unsigned short* Bp = B + (size_t)(bn + srow) * K + scol;
    const int nst = K >> 5;           // 32 for K=1024

    f32x4 acc[4][2];
#pragma unroll
    for (int r = 0; r < 4; ++r)
#pragma unroll
        for (int c = 0; c < 2; ++c) acc[r][c] = (f32x4){0.f, 0.f, 0.f, 0.f};

    // prologue: t0 -> buf0, t1 -> buf1 (4 loads in flight); wait t0 only.
    gload16(Ap, &As0[tid * 8]);
    gload16(Bp, &Bs0[tid * 8]);
    gload16(Ap + 32, &As1[tid * 8]);
    gload16(Bp + 32, &Bs1[tid * 8]);
    asm volatile("s_waitcnt vmcnt(2)" ::: "memory");
    __builtin_amdgcn_s_barrier();
    __builtin_amdgcn_sched_barrier(0);

    // main: groups of 3 steps (compile-time buffer names). Covers t=0..29
    // for nst=32; steps 30,31 in tail (buffers 0,1 since 30%3=0, 31%3=1).
    int t = 0;
    for (; t + 3 <= nst - 2; t += 3) {
        PSTEP(As0, Bs0, As2, Bs2, t);
        PSTEP(As1, Bs1, As0, Bs0, t + 1);
        PSTEP(As2, Bs2, As1, Bs1, t + 2);
    }
    // tail: t = nst-2 (buf0), nst-1 (buf1); no more prefetch.
    GSTEP(As0, Bs0);
    asm volatile("s_waitcnt vmcnt(0)" ::: "memory");
    __builtin_amdgcn_s_barrier();
    __builtin_amdgcn_sched_barrier(0);
    GSTEP(As1, Bs1);

    // C/D layout: col = lane&15, row = (lane>>4)*4 + reg
#pragma unroll
    for (int r = 0; r < 4; ++r)
#pragma unroll
        for (int c = 0; c < 2; ++c)
#pragma unroll
            for (int i = 0; i < 4; ++i) {
                const int row = bm + 64 * wr + 16 * r + quad * 4 + i;
                const int col = bn + 32 * wc + 16 * c + lm;
                const float v = acc[r][c][i] + bias[col];
                if (EPI == 0) {
                    const int b = row >> 10, t2 = row & 1023;
                    const int s3 = col >> 10, rem = col & 1023;
                    const int h = rem >> 6, d = rem & 63;
                    const size_t base = (((size_t)s3 * 4 + b) * 16 + h) * 65536;
                    const size_t off = base + (s3 == 2 ? (size_t)d * 1024 + t2
                                                       : (size_t)t2 * 64 + d);
                    outb[off] = f2bf(v);
                } else {
                    outf[(size_t)row * N + col] = v;
                }
            }
}

// ---------------- MFMA flash causal attention (R37-exact) ------------------
// 32x32 lane-local softmax, KVBLK=64 joint tiles + T13 defer-max,
// permlane32_swap P-exchange.
#define LOADK(DST, KT)                                                        \
    do {                                                                      \
        const unsigned short* kr_ = Kg + (size_t)((KT) * 32 + l5) * 64 + hi8; \
        DST[0] = *(const bf16x8*)(kr_);                                       \
        DST[1] = *(const bf16x8*)(kr_ + 16);                                  \
        DST[2] = *(const bf16x8*)(kr_ + 32);                                  \
        DST[3] = *(const bf16x8*)(kr_ + 48);                                  \
    } while (0)

// Pack + partner-exchange p[16] -> two PV B-frags (BQA, BQB), in-register.
#define PACKP(p, BQA, BQB)                                                    \
    do {                                                                      \
        unsigned Q0 = pk2(p[0], p[1]),   Q1 = pk2(p[2], p[3]);                \
        unsigned Q2 = pk2(p[4], p[5]),   Q3 = pk2(p[6], p[7]);                \
        unsigned Q4 = pk2(p[8], p[9]),   Q5 = pk2(p[10], p[11]);              \
        unsigned Q6 = pk2(p[12], p[13]), Q7 = pk2(p[14], p[15]);              \
        asm volatile("v_permlane32_swap_b32 %0, %1" : "+v"(Q0), "+v"(Q2));    \
        asm volatile("v_permlane32_swap_b32 %0, %1" : "+v"(Q1), "+v"(Q3));    \
        asm volatile("v_permlane32_swap_b32 %0, %1" : "+v"(Q4), "+v"(Q6));    \
        asm volatile("v_permlane32_swap_b32 %0, %1" : "+v"(Q5), "+v"(Q7));    \
        BQA.w[0] = Q0;  BQA.w[1] = Q1;  BQA.w[2] = Q2;  BQA.w[3] = Q3;        \
        BQB.w[0] = Q4;  BQB.w[1] = Q5;  BQB.w[2] = Q6;  BQB.w[3] = Q7;        \
    } while (0)

// Single 32-j tile (tail only; always-rescale path). Uses kA-style frag KF.
#define ATTN_TILE(KF, KT)                                                     \
    do {                                                                      \
        const int jb = (KT) * 32;                                             \
        const unsigned short* vb_ = Vtg + (size_t)l5 * 1024 + jb + hi8;       \
        const bf16x8 vf00 = *(const bf16x8*)(vb_);                            \
        const bf16x8 vf01 = *(const bf16x8*)(vb_ + 16);                       \
        const bf16x8 vf10 = *(const bf16x8*)(vb_ + 32768);                    \
        const bf16x8 vf11 = *(const bf16x8*)(vb_ + 32768 + 16);               \
        f32x16 s = {0.f};                                                     \
        _Pragma("unroll")                                                     \
        for (int t = 0; t < 4; ++t)                                           \
            s = __builtin_amdgcn_mfma_f32_32x32x16_bf16(KF[t], qf[t], s, 0, 0, 0); \
        float p[16];                                                          \
        _Pragma("unroll")                                                     \
        for (int reg = 0; reg < 16; ++reg) {                                  \
            const int j = jb + (reg & 3) + 8 * (reg >> 2) + 4 * hi;           \
            p[reg] = fmaf(s[reg], 0.125f, tb[q - j + 127]);                   \
        }                                                                     \
        if (jb + 31 > qbase) {                                                \
            _Pragma("unroll")                                                 \
            for (int reg = 0; reg < 16; ++reg) {                              \
                const int j = jb + (reg & 3) + 8 * (reg >> 2) + 4 * hi;       \
                p[reg] = (j <= q) ? p[reg] : -1e30f;                          \
            }                                                                 \
        }                                                                     \
        float mx = p[0];                                                      \
        _Pragma("unroll")                                                     \
        for (int reg = 1; reg < 16; ++reg) mx = fmaxf(mx, p[reg]);            \
        mx = fmaxf(mx, __shfl_xor(mx, 32, 64));                               \
        if (!__all(mx <= mi + 8.f)) {                                         \
            const float mnew = fmaxf(mi, mx);                                 \
            const float alpha = __expf(mi - mnew);                            \
            mi = mnew;                                                        \
            li *= alpha;                                                      \
            _Pragma("unroll")                                                 \
            for (int reg = 0; reg < 16; ++reg) {                              \
                oa0[reg] *= alpha;                                            \
                oa1[reg] *= alpha;                                            \
            }                                                                 \
        }                                                                     \
        float lsum = 0.f;                                                     \
        _Pragma("unroll")                                                     \
        for (int reg = 0; reg < 16; ++reg) {                                  \
            p[reg] = __expf(p[reg] - mi);                                     \
            lsum += p[reg];                                                   \
        }                                                                     \
        li += lsum;                                                           \
        union { unsigned w[4]; bf16x8 v; } bq0, bq1;                          \
        PACKP(p, bq0, bq1);                                                   \
        oa0 = __builtin_amdgcn_mfma_f32_32x32x16_bf16(vf00, bq0.v, oa0, 0, 0, 0); \
        oa0 = __builtin_amdgcn_mfma_f32_32x32x16_bf16(vf01, bq1.v, oa0, 0, 0, 0); \
        oa1 = __builtin_amdgcn_mfma_f32_32x32x16_bf16(vf10, bq0.v, oa1, 0, 0, 0); \
        oa1 = __builtin_amdgcn_mfma_f32_32x32x16_bf16(vf11, bq1.v, oa1, 0, 0, 0); \
    } while (0)

// Joint KVBLK=64: subtiles KT (kA) and KT+1 (kB); ONE softmax update.
#define ATTN_TILE2(KT)                                                        \
    do {                                                                      \
        const int jb = (KT) * 32;                                             \
        const unsigned short* vb_ = Vtg + (size_t)l5 * 1024 + jb + hi8;       \
        const bf16x8 vf00 = *(const bf16x8*)(vb_);                            \
        const bf16x8 vf01 = *(const bf16x8*)(vb_ + 16);                       \
        const bf16x8 vf02 = *(const bf16x8*)(vb_ + 32);                       \
        const bf16x8 vf03 = *(const bf16x8*)(vb_ + 48);                       \
        const bf16x8 vf10 = *(const bf16x8*)(vb_ + 32768);                    \
        const bf16x8 vf11 = *(const bf16x8*)(vb_ + 32768 + 16);               \
        const bf16x8 vf12 = *(const bf16x8*)(vb_ + 32768 + 32);               \
        const bf16x8 vf13 = *(const bf16x8*)(vb_ + 32768 + 48);               \
        f32x16 s0v = {0.f}, s1v = {0.f};                                      \
        _Pragma("unroll")                                                     \
        for (int t = 0; t < 4; ++t) {                                         \
            s0v = __builtin_amdgcn_mfma_f32_32x32x16_bf16(kA[t], qf[t], s0v, 0, 0, 0); \
            s1v = __builtin_amdgcn_mfma_f32_32x32x16_bf16(kB[t], qf[t], s1v, 0, 0, 0); \
        }                                                                     \
        if ((KT) + 2 < nt) LOADK(kA, (KT) + 2);                               \
        if ((KT) + 3 < nt) LOADK(kB, (KT) + 3);                               \
        float p0[16], p1[16];                                                 \
        _Pragma("unroll")                                                     \
        for (int reg = 0; reg < 16; ++reg) {                                  \
            const int jo = (reg & 3) + 8 * (reg >> 2) + 4 * hi;               \
            p0[reg] = fmaf(s0v[reg], 0.125f, tb[q - jb - jo + 127]);          \
            p1[reg] = fmaf(s1v[reg], 0.125f, tb[q - jb - 32 - jo + 127]);     \
        }                                                                     \
        if (jb + 63 > qbase) {                                                \
            _Pragma("unroll")                                                 \
            for (int reg = 0; reg < 16; ++reg) {                              \
                const int jo = (reg & 3) + 8 * (reg >> 2) + 4 * hi;           \
                p0[reg] = (jb + jo <= q) ? p0[reg] : -1e30f;                  \
                p1[reg] = (jb + 32 + jo <= q) ? p1[reg] : -1e30f;             \
            }                                                                 \
        }                                                                     \
        float mx = p0[0];                                                     \
        _Pragma("unroll")                                                     \
        for (int reg = 1; reg < 16; ++reg) mx = fmaxf(mx, p0[reg]);           \
        _Pragma("unroll")                                                     \
        for (int reg = 0; reg < 16; ++reg) mx = fmaxf(mx, p1[reg]);           \
        mx = fmaxf(mx, __shfl_xor(mx, 32, 64));                               \
        if (!__all(mx <= mi + 8.f)) {                                         \
            const float mnew = fmaxf(mi, mx);                                 \
            const float alpha = __expf(mi - mnew);                            \
            mi = mnew;                                                        \
            li *= alpha;                                                      \
            _Pragma("unroll")                                                 \
            for (int reg = 0; reg < 16; ++reg) {                              \
                oa0[reg] *= alpha;                                            \
                oa1[reg] *= alpha;                                            \
            }                                                                 \
        }                                                                     \
        float lsum = 0.f;                                                     \
        _Pragma("unroll")                                                     \
        for (int reg = 0; reg < 16; ++reg) {                                  \
            p0[reg] = __expf(p0[reg] - mi);                                   \
            p1[reg] = __expf(p1[reg] - mi);                                   \
            lsum += p0[reg] + p1[reg];                                        \
        }                                                                     \
        li += lsum;                                                           \
        union { unsigned w[4]; bf16x8 v; } bq00, bq01, bq10, bq11;            \
        PACKP(p0, bq00, bq01);                                                \
        PACKP(p1, bq10, bq11);                                                \
        oa0 = __builtin_amdgcn_mfma_f32_32x32x16_bf16(vf00, bq00.v, oa0, 0, 0, 0); \
        oa1 = __builtin_amdgcn_mfma_f32_32x32x16_bf16(vf10, bq00.v, oa1, 0, 0, 0); \
        oa0 = __builtin_amdgcn_mfma_f32_32x32x16_bf16(vf01, bq01.v, oa0, 0, 0, 0); \
        oa1 = __builtin_amdgcn_mfma_f32_32x32x16_bf16(vf11, bq01.v, oa1, 0, 0, 0); \
        oa0 = __builtin_amdgcn_mfma_f32_32x32x16_bf16(vf02, bq10.v, oa0, 0, 0, 0); \
        oa1 = __builtin_amdgcn_mfma_f32_32x32x16_bf16(vf12, bq10.v, oa1, 0, 0, 0); \
        oa0 = __builtin_amdgcn_mfma_f32_32x32x16_bf16(vf03, bq11.v, oa0, 0, 0, 0); \
        oa1 = __builtin_amdgcn_mfma_f32_32x32x16_bf16(vf13, bq11.v, oa1, 0, 0, 0); \
    } while (0)

__global__ __launch_bounds__(128) void attn_mfma(const unsigned short* __restrict__ qkvb,
                                                 const float* __restrict__ table,
                                                 unsigned short* __restrict__ y) {
    const int bh = blockIdx.x, b = bh >> 4, h = bh & 15;
    const int level = 15 - blockIdx.y;      // 15..0, longest blocks first
    const int tid = threadIdx.x, lane = tid & 63, wave = tid >> 6;  // wave 0..1
    const int l5 = lane & 31, hi = lane >> 5, hi8 = hi * 8;

    __shared__ float tb[1152];

    const unsigned short* Qg  = qkvb + ((size_t)(b)*16 + h) * 65536;       // [t][d]
    const unsigned short* Kg  = qkvb + ((size_t)(4 + b)*16 + h) * 65536;   // [t][d]
    const unsigned short* Vtg = qkvb + ((size_t)(8 + b)*16 + h) * 65536;   // [d][t]

    const int qbase = 64 * level + 32 * wave;
    const int q = qbase + l5;               // ONE query per lane
    const int nt = 2 * level + wave + 1;    // exact causal 32-j tile count

    // Q fragment (MFMA B-operand): B[col=q][k = t*16 + hi*8 + e]
    bf16x8 qf[4];
    {
        const unsigned short* qr = Qg + (size_t)q * 64 + hi8;
#pragma unroll
        for (int t = 0; t < 4; ++t) qf[t] = *(const bf16x8*)(qr + t * 16);
    }

    // tb[i] = table[(896+i)*16+h]; needed i = q-j+127 in [96, 64*level+190]
    const int tbn = 64 * level + 191;
    for (int i = tid; i < tbn; i += 128) tb[i] = table[(896 + i) * 16 + h];
    __syncthreads();  // tb ready; only block-wide sync in the kernel

    f32x16 oa0 = {0.f}, oa1 = {0.f};  // O^T d-halves: row d, col q (own lane)
    float mi = -1e30f, li = 0.f;

    bf16x8 kA[4], kB[4];
    LOADK(kA, 0);
    LOADK(kB, nt > 1 ? 1 : 0);
    int kt = 0;
    for (; kt + 1 < nt; kt += 2) ATTN_TILE2(kt);
    if (kt < nt) ATTN_TILE(kA, kt);  // odd-nt tail (kA prefetched by pair loop)

    // epilogue: li = own + partner halves (1 shfl); O^T/li -> y.
    li += __shfl_xor(li, 32, 64);
    const float linv = 1.0f / li;
    // lane's d = dh*32 + 8*g + 4*hi + (0..3)  (reg = 4g..4g+3 consecutive)
    unsigned short* yq = y + ((size_t)(b * 1024 + q)) * 1024 + h * 64;
#pragma unroll
    for (int g = 0; g < 4; ++g) {
        union { unsigned short u[4]; int2 v; } o4a, o4b;
#pragma unroll
        for (int i = 0; i < 4; ++i) {
            o4a.u[i] = f2bf(oa0[4 * g + i] * linv);
            o4b.u[i] = f2bf(oa1[4 * g + i] * linv);
        }
        *(int2*)(yq + 8 * g + 4 * hi) = o4a.v;
        *(int2*)(yq + 32 + 8 * g + 4 * hi) = o4b.v;
    }
}

extern "C" void kernel_launch(void* const* d_in, const int* in_sizes, int n_in,
                              void* d_out, int out_size, void* d_ws, size_t ws_size,
                              hipStream_t stream) {
    const float* x      = (const float*)d_in[0];
    const float* qkv_w  = (const float*)d_in[1];
    const float* qkv_b  = (const float*)d_in[2];
    const float* proj_w = (const float*)d_in[3];
    const float* proj_b = (const float*)d_in[4];
    const float* rel    = (const float*)d_in[5];
    float* out = (float*)d_out;

    char* ws = (char*)d_ws;
    unsigned short* xb   = (unsigned short*)(ws + 0);
    unsigned short* qwb  = (unsigned short*)(ws + 8388608);
    unsigned short* pwb  = (unsigned short*)(ws + 14680064);
    float* table         = (float*)(ws + 16777216);
    unsigned short* qkvb = (unsigned short*)(ws + 16908288);
    unsigned short* yb   = (unsigned short*)(ws + 42074112);

    cvt3<<<4096, 256, 0, stream>>>(x, qkv_w, proj_w, xb, qwb, pwb);
    table_reduce<<<2047, 1024, 0, stream>>>(rel, table);
    gemm_bt<0><<<dim3(32, 24), 512, 0, stream>>>(xb, qwb, qkv_b, qkvb, nullptr,
                                                 4096, 3072, 1024);
    attn_mfma<<<dim3(64, 16), 128, 0, stream>>>(qkvb, table, yb);
    gemm_bt<1><<<dim3(32, 8), 512, 0, stream>>>(yb, pwb, proj_b, nullptr, out,
                                                4096, 1024, 1024);
}